// Round 1
// baseline (1154.088 us; speedup 1.0000x reference)
//
#include <hip/hip_runtime.h>
#include <math.h>

#define NNODES 10000
#define NEDGES 160000
#define HEADS 7
#define CH 64
#define HC 448  // HEADS*CH

// ---------------------------------------------------------------------------
// Generic fp32 tiled GEMM: C = act(A @ W + bias)
// A: [M,K] row-major, W: [K,Nc] row-major, C: [M,Nc] row-major.
// Block tile 64x64, K-chunk 32, 256 threads, 4x4 register tile per thread.
// Requires: K % 32 == 0, Nc % 64 == 0. Rows are guarded/clamped.
// ---------------------------------------------------------------------------
__global__ __launch_bounds__(256) void gemm_bias_act(
    const float* __restrict__ A, const float* __restrict__ W,
    const float* __restrict__ bias, float* __restrict__ C,
    int M, int K, int Nc, int do_relu)
{
  __shared__ float As[32][64];  // [k][m]
  __shared__ float Bs[32][64];  // [k][n]
  int tid = threadIdx.x;
  int row0 = blockIdx.x * 64;
  int col0 = blockIdx.y * 64;
  int tr = (tid / 16) * 4;
  int tc = (tid % 16) * 4;
  float acc[4][4] = {};

  for (int k0 = 0; k0 < K; k0 += 32) {
    // A tile: 64 rows x 32 k, float4 along k, store transposed to As[k][m]
    #pragma unroll
    for (int s = 0; s < 2; ++s) {
      int idx = tid + s * 256;          // 0..511
      int m = idx / 8;                   // 0..63
      int k4 = idx % 8;                  // 0..7
      int row = row0 + m; if (row >= M) row = M - 1;  // clamp (writes guarded)
      float4 a4 = *(const float4*)&A[(size_t)row * K + k0 + k4 * 4];
      int kk = k4 * 4;
      As[kk + 0][m] = a4.x; As[kk + 1][m] = a4.y;
      As[kk + 2][m] = a4.z; As[kk + 3][m] = a4.w;
    }
    // B tile: 32 k x 64 n, float4 along n
    #pragma unroll
    for (int s = 0; s < 2; ++s) {
      int idx = tid + s * 256;
      int kk = idx / 16;
      int n4 = idx % 16;
      float4 b4 = *(const float4*)&W[(size_t)(k0 + kk) * Nc + col0 + n4 * 4];
      *(float4*)&Bs[kk][n4 * 4] = b4;
    }
    __syncthreads();
    #pragma unroll
    for (int kk = 0; kk < 32; ++kk) {
      float4 a4 = *(const float4*)&As[kk][tr];
      float4 b4 = *(const float4*)&Bs[kk][tc];
      float av[4] = {a4.x, a4.y, a4.z, a4.w};
      float bv[4] = {b4.x, b4.y, b4.z, b4.w};
      #pragma unroll
      for (int i = 0; i < 4; ++i)
        #pragma unroll
        for (int j = 0; j < 4; ++j)
          acc[i][j] += av[i] * bv[j];
    }
    __syncthreads();
  }

  float bj[4] = {0.f, 0.f, 0.f, 0.f};
  if (bias) {
    #pragma unroll
    for (int j = 0; j < 4; ++j) bj[j] = bias[col0 + tc + j];
  }
  #pragma unroll
  for (int i = 0; i < 4; ++i) {
    int row = row0 + tr + i;
    if (row < M) {
      float v0 = acc[i][0] + bj[0], v1 = acc[i][1] + bj[1];
      float v2 = acc[i][2] + bj[2], v3 = acc[i][3] + bj[3];
      if (do_relu) {
        v0 = fmaxf(v0, 0.f); v1 = fmaxf(v1, 0.f);
        v2 = fmaxf(v2, 0.f); v3 = fmaxf(v3, 0.f);
      }
      float4 o; o.x = v0; o.y = v1; o.z = v2; o.w = v3;
      *(float4*)&C[(size_t)row * Nc + col0 + tc] = o;
    }
  }
}

// ---------------------------------------------------------------------------
// CSR build (dst-grouped). Edges re-uploaded every call, so rebuilt per launch.
// ---------------------------------------------------------------------------
__global__ void hist_kernel(const int* __restrict__ ei, int* __restrict__ cnt) {
  int e = blockIdx.x * 256 + threadIdx.x;
  if (e < NEDGES) atomicAdd(&cnt[ei[NEDGES + e]], 1);
}

__global__ __launch_bounds__(1024) void scan_kernel(
    const int* __restrict__ cnt, int* __restrict__ row_start,
    int* __restrict__ cursor)
{
  __shared__ int buf[1024];
  __shared__ int running_s;
  int tid = threadIdx.x;
  if (tid == 0) running_s = 0;
  __syncthreads();
  for (int base = 0; base < NNODES; base += 1024) {
    int i = base + tid;
    int v = (i < NNODES) ? cnt[i] : 0;
    buf[tid] = v;
    __syncthreads();
    for (int off = 1; off < 1024; off <<= 1) {
      int t = (tid >= off) ? buf[tid - off] : 0;
      __syncthreads();
      buf[tid] += t;
      __syncthreads();
    }
    int incl = buf[tid];
    int r = running_s;
    if (i < NNODES) {
      int excl = r + incl - v;
      row_start[i] = excl;
      cursor[i] = excl;
    }
    __syncthreads();
    if (tid == 1023) running_s = r + incl;
    __syncthreads();
  }
  if (tid == 0) row_start[NNODES] = running_s;
}

__global__ void scatter_kernel(const int* __restrict__ ei,
                               int* __restrict__ cursor,
                               int* __restrict__ csr_src) {
  int e = blockIdx.x * 256 + threadIdx.x;
  if (e < NEDGES) {
    int d = ei[NEDGES + e];
    int pos = atomicAdd(&cursor[d], 1);
    csr_src[pos] = ei[e];
  }
}

// ---------------------------------------------------------------------------
// Fused GATv2 aggregation: one wave per dst node, online softmax over its
// incoming edges (+ implicit self-loop). lane = channel c (64), loop heads.
// Epilogue: out[h]/l[h], mean over heads, +cbias, relu.
// ---------------------------------------------------------------------------
__device__ __forceinline__ float wave_sum(float p) {
  #pragma unroll
  for (int msk = 32; msk >= 1; msk >>= 1) p += __shfl_xor(p, msk, 64);
  return p;
}

__global__ __launch_bounds__(256) void gat_agg_kernel(
    const float* __restrict__ xl, const float* __restrict__ xr,
    const float* __restrict__ att, const float* __restrict__ cbias,
    const int* __restrict__ row_start, const int* __restrict__ csr_src,
    float* __restrict__ hout)
{
  int lane = threadIdx.x & 63;
  int wid = threadIdx.x >> 6;
  int n = blockIdx.x * 4 + wid;
  if (n >= NNODES) return;

  float att_r[HEADS], xr_r[HEADS], out[HEADS], m[HEADS], l[HEADS];
  #pragma unroll
  for (int h = 0; h < HEADS; ++h) att_r[h] = att[h * 64 + lane];
  #pragma unroll
  for (int h = 0; h < HEADS; ++h) xr_r[h] = xr[(size_t)n * HC + h * 64 + lane];

  // self loop (src == dst == n)
  #pragma unroll
  for (int h = 0; h < HEADS; ++h) {
    float xls = xl[(size_t)n * HC + h * 64 + lane];
    float t = xls + xr_r[h];
    t = (t > 0.f) ? t : 0.2f * t;
    float p = wave_sum(t * att_r[h]);
    m[h] = p; l[h] = 1.0f; out[h] = xls;
  }

  int beg = row_start[n], end = row_start[n + 1];
  for (int e = beg; e < end; ++e) {
    int s = csr_src[e];
    const float* xlp = &xl[(size_t)s * HC + lane];
    float xls[HEADS];
    #pragma unroll
    for (int h = 0; h < HEADS; ++h) xls[h] = xlp[h * 64];
    #pragma unroll
    for (int h = 0; h < HEADS; ++h) {
      float t = xls[h] + xr_r[h];
      t = (t > 0.f) ? t : 0.2f * t;
      float p = wave_sum(t * att_r[h]);
      // wave-uniform branch (p identical across lanes)
      if (p <= m[h]) {
        float w = __expf(p - m[h]);
        out[h] += w * xls[h];
        l[h] += w;
      } else {
        float sc = __expf(m[h] - p);
        out[h] = out[h] * sc + xls[h];
        l[h] = l[h] * sc + 1.0f;
        m[h] = p;
      }
    }
  }

  float acc = 0.f;
  #pragma unroll
  for (int h = 0; h < HEADS; ++h) acc += out[h] / (l[h] + 1e-16f);
  float v = acc * (1.0f / 7.0f) + cbias[lane];
  hout[(size_t)n * 64 + lane] = fmaxf(v, 0.f);
}

// ---------------------------------------------------------------------------
// Output MLP 64->32->16->9 + log_softmax, one 64-thread block per node.
// Note: h already has relu applied; relu applies to z1, z2 only.
// ---------------------------------------------------------------------------
__global__ __launch_bounds__(64) void out_mlp_kernel(
    const float* __restrict__ h,
    const float* __restrict__ V1, const float* __restrict__ c1,
    const float* __restrict__ V2, const float* __restrict__ c2,
    const float* __restrict__ V3, const float* __restrict__ c3,
    float* __restrict__ out)
{
  __shared__ float hb[64], r1[32], r2[16], z3[9];
  int n = blockIdx.x;
  int t = threadIdx.x;
  hb[t] = h[(size_t)n * 64 + t];
  __syncthreads();
  if (t < 32) {
    float a = c1[t];
    #pragma unroll
    for (int k = 0; k < 64; ++k) a += hb[k] * V1[k * 32 + t];
    r1[t] = fmaxf(a, 0.f);
  }
  __syncthreads();
  if (t < 16) {
    float a = c2[t];
    #pragma unroll
    for (int k = 0; k < 32; ++k) a += r1[k] * V2[k * 16 + t];
    r2[t] = fmaxf(a, 0.f);
  }
  __syncthreads();
  if (t < 9) {
    float a = c3[t];
    #pragma unroll
    for (int k = 0; k < 16; ++k) a += r2[k] * V3[k * 9 + t];
    z3[t] = a;
  }
  __syncthreads();
  if (t < 9) {
    float mx = z3[0];
    #pragma unroll
    for (int k = 1; k < 9; ++k) mx = fmaxf(mx, z3[k]);
    float s = 0.f;
    #pragma unroll
    for (int k = 0; k < 9; ++k) s += __expf(z3[k] - mx);
    out[(size_t)n * 9 + t] = z3[t] - mx - logf(s);
  }
}

// ---------------------------------------------------------------------------
extern "C" void kernel_launch(void* const* d_in, const int* in_sizes, int n_in,
                              void* d_out, int out_size, void* d_ws, size_t ws_size,
                              hipStream_t stream) {
  const float* x   = (const float*)d_in[0];
  const int*   ei  = (const int*)d_in[1];   // [2,E]: src = ei[0..E), dst = ei[E..2E)
  const float* W1  = (const float*)d_in[2];
  const float* b1  = (const float*)d_in[3];
  const float* W2  = (const float*)d_in[4];
  const float* b2  = (const float*)d_in[5];
  const float* W3  = (const float*)d_in[6];
  const float* b3  = (const float*)d_in[7];
  const float* Wl  = (const float*)d_in[8];
  const float* bl  = (const float*)d_in[9];
  const float* Wr  = (const float*)d_in[10];
  const float* att = (const float*)d_in[11];
  const float* cb  = (const float*)d_in[12];
  const float* V1  = (const float*)d_in[13];
  const float* c1  = (const float*)d_in[14];
  const float* V2  = (const float*)d_in[15];
  const float* c2  = (const float*)d_in[16];
  const float* V3  = (const float*)d_in[17];
  const float* c3  = (const float*)d_in[18];
  float* out = (float*)d_out;

  char* ws = (char*)d_ws;
  size_t off = 0;
  auto alloc = [&](size_t bytes) {
    void* p = ws + off;
    off = (off + bytes + 255) & ~(size_t)255;
    return p;
  };
  float* h1        = (float*)alloc((size_t)NNODES * 512 * 4);
  float* h2        = (float*)alloc((size_t)NNODES * 256 * 4);
  float* hA        = (float*)alloc((size_t)NNODES * 64 * 4);
  float* hB        = (float*)alloc((size_t)NNODES * 64 * 4);
  float* xl        = (float*)alloc((size_t)NNODES * HC * 4);
  float* xr        = (float*)alloc((size_t)NNODES * HC * 4);
  int*   cnt       = (int*)alloc((size_t)NNODES * 4);
  int*   row_start = (int*)alloc((size_t)(NNODES + 1) * 4);
  int*   cursor    = (int*)alloc((size_t)NNODES * 4);
  int*   csr_src   = (int*)alloc((size_t)NEDGES * 4);

  // CSR build (ws is re-poisoned 0xAA before every launch -> must zero cnt)
  hipMemsetAsync(cnt, 0, NNODES * 4, stream);
  hist_kernel<<<(NEDGES + 255) / 256, 256, 0, stream>>>(ei, cnt);
  scan_kernel<<<1, 1024, 0, stream>>>(cnt, row_start, cursor);
  scatter_kernel<<<(NEDGES + 255) / 256, 256, 0, stream>>>(ei, cursor, csr_src);

  // input MLP
  gemm_bias_act<<<dim3(157, 8), 256, 0, stream>>>(x,  W1, b1, h1, NNODES, 1024, 512, 1);
  gemm_bias_act<<<dim3(157, 4), 256, 0, stream>>>(h1, W2, b2, h2, NNODES, 512, 256, 1);
  gemm_bias_act<<<dim3(157, 1), 256, 0, stream>>>(h2, W3, b3, hA, NNODES, 256, 64, 1);

  // 5 GATv2 layers
  float* hcur = hA; float* hnext = hB;
  for (int layer = 0; layer < 5; ++layer) {
    gemm_bias_act<<<dim3(157, 7), 256, 0, stream>>>(
        hcur, Wl + (size_t)layer * 64 * HC, bl + (size_t)layer * HC, xl,
        NNODES, 64, HC, 0);
    gemm_bias_act<<<dim3(157, 7), 256, 0, stream>>>(
        hcur, Wr + (size_t)layer * 64 * HC, nullptr, xr,
        NNODES, 64, HC, 0);
    gat_agg_kernel<<<2500, 256, 0, stream>>>(
        xl, xr, att + (size_t)layer * HC, cb + (size_t)layer * 64,
        row_start, csr_src, hnext);
    float* tmp = hcur; hcur = hnext; hnext = tmp;
  }

  // output MLP + log_softmax
  out_mlp_kernel<<<NNODES, 64, 0, stream>>>(hcur, V1, c1, V2, c2, V3, c3, out);
}

// Round 2
// 1019.680 us; speedup vs baseline: 1.1318x; 1.1318x over previous
//
#include <hip/hip_runtime.h>
#include <hip/hip_bf16.h>
#include <math.h>

#define NNODES 10000
#define NEDGES 160000
#define HEADS 7
#define CH 64
#define HC 448   // HEADS*CH
#define HC2 896  // xl|xr fused

typedef __attribute__((ext_vector_type(8))) short short8;
typedef __attribute__((ext_vector_type(4))) float floatx4;

// ---------------------------------------------------------------------------
// Conversion / packing kernels (ws is re-poisoned every call -> repack per launch)
// ---------------------------------------------------------------------------
__global__ __launch_bounds__(256) void convert_f32_bf16(
    const float* __restrict__ in, short* __restrict__ out, int n4) {
  int i = blockIdx.x * 256 + threadIdx.x;
  if (i < n4) {
    float4 v = *(const float4*)&in[(size_t)i * 4];
    short4 o;
    o.x = __bfloat16_as_short(__float2bfloat16(v.x));
    o.y = __bfloat16_as_short(__float2bfloat16(v.y));
    o.z = __bfloat16_as_short(__float2bfloat16(v.z));
    o.w = __bfloat16_as_short(__float2bfloat16(v.w));
    *(short4*)&out[(size_t)i * 4] = o;
  }
}

// out[n*K+k] = bf16(in[k*N+n])   (W [K,N] row-major -> Wt [N,K] row-major)
__global__ __launch_bounds__(256) void transpose_bf16(
    const float* __restrict__ in, short* __restrict__ out, int K, int N) {
  int idx = blockIdx.x * 256 + threadIdx.x;
  if (idx < K * N) {
    int n = idx / K, k = idx % K;
    out[idx] = __bfloat16_as_short(__float2bfloat16(in[(size_t)k * N + n]));
  }
}

// Pack Wl|Wr for all 5 layers into [5][896][64] bf16 (transposed), plus fused bias
__global__ __launch_bounds__(256) void pack_gat(
    const float* __restrict__ Wl, const float* __restrict__ Wr,
    const float* __restrict__ bl, short* __restrict__ Wgt,
    float* __restrict__ bg) {
  int idx = blockIdx.x * 256 + threadIdx.x;
  if (idx < 5 * HC2 * 64) {
    int l = idx / (HC2 * 64);
    int rem = idx % (HC2 * 64);
    int n = rem / 64, k = rem % 64;
    float v = (n < HC) ? Wl[((size_t)l * 64 + k) * HC + n]
                       : Wr[((size_t)l * 64 + k) * HC + (n - HC)];
    Wgt[idx] = __bfloat16_as_short(__float2bfloat16(v));
  }
  if (idx < 5 * HC2) {
    int l = idx / HC2, n = idx % HC2;
    bg[idx] = (n < HC) ? bl[(size_t)l * HC + n] : 0.f;
  }
}

// ---------------------------------------------------------------------------
// MFMA bf16 GEMM: C = act(A @ Bt^T + bias)
// A: [M,K] bf16 row-major. Bt: [Nc,K] bf16 row-major (i.e. B transposed).
// C: [M,Nc] bf16 or fp32. Tile 128x128, BK=64, 256 thr (4 waves, 2x2),
// mfma 16x16x32, global_load_lds width=16. K % 64 == 0 required.
// ---------------------------------------------------------------------------
__device__ __forceinline__ void stage_tile(
    const short* __restrict__ g, int rows_total, int K, int row0, int k0,
    short* lds, int wave, int lane) {
  #pragma unroll
  for (int i = 0; i < 4; ++i) {
    int c = i * 4 + wave;              // chunk 0..15 (1 KiB each)
    int r = c * 8 + (lane >> 3);       // tile row 0..127
    int k = (lane & 7) * 8;            // k elem offset
    int grow = row0 + r;
    if (grow >= rows_total) grow = rows_total - 1;  // clamp; stores guarded
    const short* gp = g + (size_t)grow * K + k0 + k;
    short* lp = lds + c * 512;         // wave-uniform base; lanes fill +lane*16B
    __builtin_amdgcn_global_load_lds(
        (const __attribute__((address_space(1))) void*)gp,
        (__attribute__((address_space(3))) void*)lp, 16, 0, 0);
  }
}

template <int OUT_BF16, int RELU>
__global__ __launch_bounds__(256) void mfma_gemm(
    const short* __restrict__ A, const short* __restrict__ Bt,
    const float* __restrict__ bias, void* __restrict__ C,
    int M, int K, int Nc) {
  __shared__ short As[128 * 64];
  __shared__ short Bs[128 * 64];
  int tid = threadIdx.x;
  int lane = tid & 63, wave = tid >> 6;
  int wm = wave >> 1, wn = wave & 1;
  int row0 = blockIdx.x * 128, col0 = blockIdx.y * 128;
  floatx4 acc[4][4] = {};

  for (int k0 = 0; k0 < K; k0 += 64) {
    stage_tile(A, M, K, row0, k0, As, wave, lane);
    stage_tile(Bt, Nc, K, col0, k0, Bs, wave, lane);
    __syncthreads();
    int lr = lane & 15, lq = lane >> 4;
    #pragma unroll
    for (int kk = 0; kk < 64; kk += 32) {
      short8 af[4], bf[4];
      #pragma unroll
      for (int i = 0; i < 4; ++i)
        af[i] = *(const short8*)&As[(wm * 64 + i * 16 + lr) * 64 + kk + lq * 8];
      #pragma unroll
      for (int j = 0; j < 4; ++j)
        bf[j] = *(const short8*)&Bs[(wn * 64 + j * 16 + lr) * 64 + kk + lq * 8];
      #pragma unroll
      for (int i = 0; i < 4; ++i)
        #pragma unroll
        for (int j = 0; j < 4; ++j)
          acc[i][j] = __builtin_amdgcn_mfma_f32_16x16x32_bf16(
              af[i], bf[j], acc[i][j], 0, 0, 0);
    }
    __syncthreads();
  }

  int lr = lane & 15, lq = lane >> 4;
  #pragma unroll
  for (int j = 0; j < 4; ++j) {
    int col = col0 + wn * 64 + j * 16 + lr;
    if (col >= Nc) continue;
    float bj = bias ? bias[col] : 0.f;
    #pragma unroll
    for (int i = 0; i < 4; ++i) {
      int rbase = row0 + wm * 64 + i * 16 + lq * 4;
      #pragma unroll
      for (int r = 0; r < 4; ++r) {
        int row = rbase + r;
        if (row < M) {
          float v = acc[i][j][r] + bj;
          if (RELU) v = fmaxf(v, 0.f);
          if (OUT_BF16)
            ((__hip_bfloat16*)C)[(size_t)row * Nc + col] = __float2bfloat16(v);
          else
            ((float*)C)[(size_t)row * Nc + col] = v;
        }
      }
    }
  }
}

// ---------------------------------------------------------------------------
// CSR build (dst-grouped).
// ---------------------------------------------------------------------------
__global__ void hist_kernel(const int* __restrict__ ei, int* __restrict__ cnt) {
  int e = blockIdx.x * 256 + threadIdx.x;
  if (e < NEDGES) atomicAdd(&cnt[ei[NEDGES + e]], 1);
}

__global__ __launch_bounds__(1024) void scan_kernel(
    const int* __restrict__ cnt, int* __restrict__ row_start,
    int* __restrict__ cursor) {
  __shared__ int buf[1024];
  __shared__ int running_s;
  int tid = threadIdx.x;
  if (tid == 0) running_s = 0;
  __syncthreads();
  for (int base = 0; base < NNODES; base += 1024) {
    int i = base + tid;
    int v = (i < NNODES) ? cnt[i] : 0;
    buf[tid] = v;
    __syncthreads();
    for (int off = 1; off < 1024; off <<= 1) {
      int t = (tid >= off) ? buf[tid - off] : 0;
      __syncthreads();
      buf[tid] += t;
      __syncthreads();
    }
    int incl = buf[tid];
    int r = running_s;
    if (i < NNODES) {
      int excl = r + incl - v;
      row_start[i] = excl;
      cursor[i] = excl;
    }
    __syncthreads();
    if (tid == 1023) running_s = r + incl;
    __syncthreads();
  }
  if (tid == 0) row_start[NNODES] = running_s;
}

__global__ void scatter_kernel(const int* __restrict__ ei,
                               int* __restrict__ cursor,
                               int* __restrict__ csr_src) {
  int e = blockIdx.x * 256 + threadIdx.x;
  if (e < NEDGES) {
    int d = ei[NEDGES + e];
    int pos = atomicAdd(&cursor[d], 1);
    csr_src[pos] = ei[e];
  }
}

// ---------------------------------------------------------------------------
// Fused GATv2 aggregation, one wave per dst node, online softmax.
// xlr: [N][896] bf16 (cols 0..447 = xl, 448..895 = xr). hout: [N][64] bf16.
// ---------------------------------------------------------------------------
__device__ __forceinline__ float wave_sum(float p) {
  #pragma unroll
  for (int msk = 32; msk >= 1; msk >>= 1) p += __shfl_xor(p, msk, 64);
  return p;
}

__global__ __launch_bounds__(256) void gat_agg_kernel(
    const short* __restrict__ xlr, const float* __restrict__ att,
    const float* __restrict__ cbias, const int* __restrict__ row_start,
    const int* __restrict__ csr_src, short* __restrict__ hout) {
  int lane = threadIdx.x & 63;
  int wid = threadIdx.x >> 6;
  int n = blockIdx.x * 4 + wid;
  if (n >= NNODES) return;

  float att_r[HEADS], xr_r[HEADS], out[HEADS], m[HEADS], l[HEADS];
  #pragma unroll
  for (int h = 0; h < HEADS; ++h) att_r[h] = att[h * 64 + lane];
  const short* xrp0 = &xlr[(size_t)n * HC2 + HC + lane];
  #pragma unroll
  for (int h = 0; h < HEADS; ++h)
    xr_r[h] = __bfloat162float(__short_as_bfloat16(xrp0[h * 64]));

  // self loop
  const short* xlp0 = &xlr[(size_t)n * HC2 + lane];
  #pragma unroll
  for (int h = 0; h < HEADS; ++h) {
    float xls = __bfloat162float(__short_as_bfloat16(xlp0[h * 64]));
    float t = xls + xr_r[h];
    t = (t > 0.f) ? t : 0.2f * t;
    float p = wave_sum(t * att_r[h]);
    m[h] = p; l[h] = 1.0f; out[h] = xls;
  }

  int beg = row_start[n], end = row_start[n + 1];
  for (int e = beg; e < end; ++e) {
    int s = csr_src[e];
    const short* xlp = &xlr[(size_t)s * HC2 + lane];
    float xls[HEADS];
    #pragma unroll
    for (int h = 0; h < HEADS; ++h)
      xls[h] = __bfloat162float(__short_as_bfloat16(xlp[h * 64]));
    #pragma unroll
    for (int h = 0; h < HEADS; ++h) {
      float t = xls[h] + xr_r[h];
      t = (t > 0.f) ? t : 0.2f * t;
      float p = wave_sum(t * att_r[h]);
      if (p <= m[h]) {            // wave-uniform branch
        float w = __expf(p - m[h]);
        out[h] += w * xls[h];
        l[h] += w;
      } else {
        float sc = __expf(m[h] - p);
        out[h] = out[h] * sc + xls[h];
        l[h] = l[h] * sc + 1.0f;
        m[h] = p;
      }
    }
  }

  float acc = 0.f;
  #pragma unroll
  for (int h = 0; h < HEADS; ++h) acc += out[h] / (l[h] + 1e-16f);
  float v = acc * (1.0f / 7.0f) + cbias[lane];
  hout[(size_t)n * 64 + lane] =
      __bfloat16_as_short(__float2bfloat16(fmaxf(v, 0.f)));
}

// ---------------------------------------------------------------------------
// Output MLP 64->32->16->9 + log_softmax, one 64-thread block per node.
// ---------------------------------------------------------------------------
__global__ __launch_bounds__(64) void out_mlp_kernel(
    const short* __restrict__ h, const float* __restrict__ V1,
    const float* __restrict__ c1, const float* __restrict__ V2,
    const float* __restrict__ c2, const float* __restrict__ V3,
    const float* __restrict__ c3, float* __restrict__ out) {
  __shared__ float hb[64], r1[32], r2[16], z3[9];
  int n = blockIdx.x;
  int t = threadIdx.x;
  hb[t] = __bfloat162float(__short_as_bfloat16(h[(size_t)n * 64 + t]));
  __syncthreads();
  if (t < 32) {
    float a = c1[t];
    #pragma unroll
    for (int k = 0; k < 64; ++k) a += hb[k] * V1[k * 32 + t];
    r1[t] = fmaxf(a, 0.f);
  }
  __syncthreads();
  if (t < 16) {
    float a = c2[t];
    #pragma unroll
    for (int k = 0; k < 32; ++k) a += r1[k] * V2[k * 16 + t];
    r2[t] = fmaxf(a, 0.f);
  }
  __syncthreads();
  if (t < 9) {
    float a = c3[t];
    #pragma unroll
    for (int k = 0; k < 16; ++k) a += r2[k] * V3[k * 9 + t];
    z3[t] = a;
  }
  __syncthreads();
  if (t < 9) {
    float mx = z3[0];
    #pragma unroll
    for (int k = 1; k < 9; ++k) mx = fmaxf(mx, z3[k]);
    float s = 0.f;
    #pragma unroll
    for (int k = 0; k < 9; ++k) s += __expf(z3[k] - mx);
    out[(size_t)n * 9 + t] = z3[t] - mx - logf(s);
  }
}

// ---------------------------------------------------------------------------
extern "C" void kernel_launch(void* const* d_in, const int* in_sizes, int n_in,
                              void* d_out, int out_size, void* d_ws, size_t ws_size,
                              hipStream_t stream) {
  const float* x   = (const float*)d_in[0];
  const int*   ei  = (const int*)d_in[1];
  const float* W1  = (const float*)d_in[2];
  const float* b1  = (const float*)d_in[3];
  const float* W2  = (const float*)d_in[4];
  const float* b2  = (const float*)d_in[5];
  const float* W3  = (const float*)d_in[6];
  const float* b3  = (const float*)d_in[7];
  const float* Wl  = (const float*)d_in[8];
  const float* bl  = (const float*)d_in[9];
  const float* Wr  = (const float*)d_in[10];
  const float* att = (const float*)d_in[11];
  const float* cb  = (const float*)d_in[12];
  const float* V1  = (const float*)d_in[13];
  const float* c1  = (const float*)d_in[14];
  const float* V2  = (const float*)d_in[15];
  const float* c2  = (const float*)d_in[16];
  const float* V3  = (const float*)d_in[17];
  const float* c3  = (const float*)d_in[18];
  float* out = (float*)d_out;

  char* ws = (char*)d_ws;
  size_t off = 0;
  auto alloc = [&](size_t bytes) {
    void* p = ws + off;
    off = (off + bytes + 255) & ~(size_t)255;
    return p;
  };
  // region0 (reused): xb (20.5MB) -> h2 (5.1MB) -> xlr (17.9MB)
  char* region0 = (char*)alloc((size_t)NNODES * 1024 * 2 + 1024);
  short* xb  = (short*)region0;                  // [N,1024] bf16
  short* h2  = (short*)region0;                  // [N,256]  bf16 (xb dead)
  short* xlr = (short*)region0;                  // [N,896]  bf16 (h2 dead)
  // region1 (reused): h1 (10.2MB) -> hA/hB
  char* region1 = (char*)alloc((size_t)NNODES * 512 * 2 + 1024);
  short* h1 = (short*)region1;                   // [N,512] bf16
  short* hA = (short*)region1;                   // [N,64]  bf16 (h1 dead)
  short* hB = hA + (size_t)NNODES * 64;
  // persistent packs
  short* W1t = (short*)alloc((size_t)512 * 1024 * 2);
  short* W2t = (short*)alloc((size_t)256 * 512 * 2);
  short* W3t = (short*)alloc((size_t)64 * 256 * 2);
  short* Wgt = (short*)alloc((size_t)5 * HC2 * 64 * 2);
  float* bg  = (float*)alloc((size_t)5 * HC2 * 4);
  int* cnt       = (int*)alloc((size_t)NNODES * 4);
  int* row_start = (int*)alloc((size_t)(NNODES + 1) * 4);
  int* cursor    = (int*)alloc((size_t)NNODES * 4);
  int* csr_src   = (int*)alloc((size_t)NEDGES * 4);

  // ---- pack / convert
  convert_f32_bf16<<<(NNODES * 1024 / 4 + 255) / 256, 256, 0, stream>>>(
      x, xb, NNODES * 1024 / 4);
  transpose_bf16<<<(1024 * 512 + 255) / 256, 256, 0, stream>>>(W1, W1t, 1024, 512);
  transpose_bf16<<<(512 * 256 + 255) / 256, 256, 0, stream>>>(W2, W2t, 512, 256);
  transpose_bf16<<<(256 * 64 + 255) / 256, 256, 0, stream>>>(W3, W3t, 256, 64);
  pack_gat<<<(5 * HC2 * 64 + 255) / 256, 256, 0, stream>>>(Wl, Wr, bl, Wgt, bg);

  // ---- CSR build
  hipMemsetAsync(cnt, 0, NNODES * 4, stream);
  hist_kernel<<<(NEDGES + 255) / 256, 256, 0, stream>>>(ei, cnt);
  scan_kernel<<<1, 1024, 0, stream>>>(cnt, row_start, cursor);
  scatter_kernel<<<(NEDGES + 255) / 256, 256, 0, stream>>>(ei, cursor, csr_src);

  // ---- input MLP (bf16 MFMA)
  mfma_gemm<1, 1><<<dim3(79, 4), 256, 0, stream>>>(xb, W1t, b1, h1, NNODES, 1024, 512);
  mfma_gemm<1, 1><<<dim3(79, 2), 256, 0, stream>>>(h1, W2t, b2, h2, NNODES, 512, 256);
  mfma_gemm<1, 1><<<dim3(79, 1), 256, 0, stream>>>(h2, W3t, b3, hA, NNODES, 256, 64);

  // ---- 5 GATv2 layers
  short* hcur = hA;
  short* hnext = hB;
  for (int layer = 0; layer < 5; ++layer) {
    mfma_gemm<1, 0><<<dim3(79, 7), 256, 0, stream>>>(
        hcur, Wgt + (size_t)layer * HC2 * 64, bg + (size_t)layer * HC2, xlr,
        NNODES, 64, HC2);
    gat_agg_kernel<<<2500, 256, 0, stream>>>(
        xlr, att + (size_t)layer * HC, cb + (size_t)layer * 64,
        row_start, csr_src, hnext);
    short* tmp = hcur; hcur = hnext; hnext = tmp;
  }

  // ---- output MLP + log_softmax
  out_mlp_kernel<<<NNODES, 64, 0, stream>>>(hcur, V1, c1, V2, c2, V3, c3, out);
}

// Round 3
// 804.680 us; speedup vs baseline: 1.4342x; 1.2672x over previous
//
#include <hip/hip_runtime.h>
#include <hip/hip_bf16.h>
#include <math.h>

#define NNODES 10000
#define NEDGES 160000
#define ETOT (NEDGES + NNODES)  // edges + self-loops
#define HEADS 7
#define CH 64
#define HC 448   // HEADS*CH
#define HC2 896  // xl|xr fused

typedef __attribute__((ext_vector_type(8))) short short8;
typedef __attribute__((ext_vector_type(4))) float floatx4;

__device__ __forceinline__ float bf_lo(unsigned u) {
  return __uint_as_float(u << 16);
}
__device__ __forceinline__ float bf_hi(unsigned u) {
  return __uint_as_float(u & 0xffff0000u);
}
__device__ __forceinline__ float bf1(unsigned short u) {
  return __uint_as_float(((unsigned)u) << 16);
}

// ---------------------------------------------------------------------------
// Conversion / packing kernels
// ---------------------------------------------------------------------------
__global__ __launch_bounds__(256) void convert_f32_bf16(
    const float* __restrict__ in, short* __restrict__ out, int n4) {
  int i = blockIdx.x * 256 + threadIdx.x;
  if (i < n4) {
    float4 v = *(const float4*)&in[(size_t)i * 4];
    short4 o;
    o.x = __bfloat16_as_short(__float2bfloat16(v.x));
    o.y = __bfloat16_as_short(__float2bfloat16(v.y));
    o.z = __bfloat16_as_short(__float2bfloat16(v.z));
    o.w = __bfloat16_as_short(__float2bfloat16(v.w));
    *(short4*)&out[(size_t)i * 4] = o;
  }
}

__global__ __launch_bounds__(256) void transpose_bf16(
    const float* __restrict__ in, short* __restrict__ out, int K, int N) {
  int idx = blockIdx.x * 256 + threadIdx.x;
  if (idx < K * N) {
    int n = idx / K, k = idx % K;
    out[idx] = __bfloat16_as_short(__float2bfloat16(in[(size_t)k * N + n]));
  }
}

__global__ __launch_bounds__(256) void pack_gat(
    const float* __restrict__ Wl, const float* __restrict__ Wr,
    const float* __restrict__ bl, short* __restrict__ Wgt,
    float* __restrict__ bg) {
  int idx = blockIdx.x * 256 + threadIdx.x;
  if (idx < 5 * HC2 * 64) {
    int l = idx / (HC2 * 64);
    int rem = idx % (HC2 * 64);
    int n = rem / 64, k = rem % 64;
    float v = (n < HC) ? Wl[((size_t)l * 64 + k) * HC + n]
                       : Wr[((size_t)l * 64 + k) * HC + (n - HC)];
    Wgt[idx] = __bfloat16_as_short(__float2bfloat16(v));
  }
  if (idx < 5 * HC2) {
    int l = idx / HC2, n = idx % HC2;
    bg[idx] = (n < HC) ? bl[(size_t)l * HC + n] : 0.f;
  }
}

// ---------------------------------------------------------------------------
// MFMA bf16 GEMM (unchanged from R2): C = act(A @ Bt^T + bias)
// ---------------------------------------------------------------------------
__device__ __forceinline__ void stage_tile(
    const short* __restrict__ g, int rows_total, int K, int row0, int k0,
    short* lds, int wave, int lane) {
  #pragma unroll
  for (int i = 0; i < 4; ++i) {
    int c = i * 4 + wave;
    int r = c * 8 + (lane >> 3);
    int k = (lane & 7) * 8;
    int grow = row0 + r;
    if (grow >= rows_total) grow = rows_total - 1;
    const short* gp = g + (size_t)grow * K + k0 + k;
    short* lp = lds + c * 512;
    __builtin_amdgcn_global_load_lds(
        (const __attribute__((address_space(1))) void*)gp,
        (__attribute__((address_space(3))) void*)lp, 16, 0, 0);
  }
}

template <int OUT_BF16, int RELU>
__global__ __launch_bounds__(256) void mfma_gemm(
    const short* __restrict__ A, const short* __restrict__ Bt,
    const float* __restrict__ bias, void* __restrict__ C,
    int M, int K, int Nc) {
  __shared__ short As[128 * 64];
  __shared__ short Bs[128 * 64];
  int tid = threadIdx.x;
  int lane = tid & 63, wave = tid >> 6;
  int wm = wave >> 1, wn = wave & 1;
  int row0 = blockIdx.x * 128, col0 = blockIdx.y * 128;
  floatx4 acc[4][4] = {};

  for (int k0 = 0; k0 < K; k0 += 64) {
    stage_tile(A, M, K, row0, k0, As, wave, lane);
    stage_tile(Bt, Nc, K, col0, k0, Bs, wave, lane);
    __syncthreads();
    int lr = lane & 15, lq = lane >> 4;
    #pragma unroll
    for (int kk = 0; kk < 64; kk += 32) {
      short8 af[4], bf[4];
      #pragma unroll
      for (int i = 0; i < 4; ++i)
        af[i] = *(const short8*)&As[(wm * 64 + i * 16 + lr) * 64 + kk + lq * 8];
      #pragma unroll
      for (int j = 0; j < 4; ++j)
        bf[j] = *(const short8*)&Bs[(wn * 64 + j * 16 + lr) * 64 + kk + lq * 8];
      #pragma unroll
      for (int i = 0; i < 4; ++i)
        #pragma unroll
        for (int j = 0; j < 4; ++j)
          acc[i][j] = __builtin_amdgcn_mfma_f32_16x16x32_bf16(
              af[i], bf[j], acc[i][j], 0, 0, 0);
    }
    __syncthreads();
  }

  int lr = lane & 15, lq = lane >> 4;
  #pragma unroll
  for (int j = 0; j < 4; ++j) {
    int col = col0 + wn * 64 + j * 16 + lr;
    if (col >= Nc) continue;
    float bj = bias ? bias[col] : 0.f;
    #pragma unroll
    for (int i = 0; i < 4; ++i) {
      int rbase = row0 + wm * 64 + i * 16 + lq * 4;
      #pragma unroll
      for (int r = 0; r < 4; ++r) {
        int row = rbase + r;
        if (row < M) {
          float v = acc[i][j][r] + bj;
          if (RELU) v = fmaxf(v, 0.f);
          if (OUT_BF16)
            ((__hip_bfloat16*)C)[(size_t)row * Nc + col] = __float2bfloat16(v);
          else
            ((float*)C)[(size_t)row * Nc + col] = v;
        }
      }
    }
  }
}

// ---------------------------------------------------------------------------
// CSR build (dst-grouped, self-loops included).
// ---------------------------------------------------------------------------
__global__ void init_cnt(int* __restrict__ cnt) {
  int i = blockIdx.x * 256 + threadIdx.x;
  if (i < NNODES) cnt[i] = 1;  // self-loop
}

__global__ void hist_kernel(const int* __restrict__ ei, int* __restrict__ cnt) {
  int e = blockIdx.x * 256 + threadIdx.x;
  if (e < NEDGES) atomicAdd(&cnt[ei[NEDGES + e]], 1);
}

__global__ __launch_bounds__(1024) void scan_kernel(
    const int* __restrict__ cnt, int* __restrict__ row_start,
    int* __restrict__ cursor) {
  __shared__ int buf[1024];
  __shared__ int running_s;
  int tid = threadIdx.x;
  if (tid == 0) running_s = 0;
  __syncthreads();
  for (int base = 0; base < NNODES; base += 1024) {
    int i = base + tid;
    int v = (i < NNODES) ? cnt[i] : 0;
    buf[tid] = v;
    __syncthreads();
    for (int off = 1; off < 1024; off <<= 1) {
      int t = (tid >= off) ? buf[tid - off] : 0;
      __syncthreads();
      buf[tid] += t;
      __syncthreads();
    }
    int incl = buf[tid];
    int r = running_s;
    if (i < NNODES) {
      int excl = r + incl - v;
      row_start[i] = excl;
      cursor[i] = excl;
    }
    __syncthreads();
    if (tid == 1023) running_s = r + incl;
    __syncthreads();
  }
  if (tid == 0) row_start[NNODES] = running_s;
}

__global__ void scatter_self(int* __restrict__ cursor,
                             int* __restrict__ csr_src,
                             int* __restrict__ csr_dst) {
  int n = blockIdx.x * 256 + threadIdx.x;
  if (n < NNODES) {
    int pos = atomicAdd(&cursor[n], 1);
    csr_src[pos] = n;
    csr_dst[pos] = n;
  }
}

__global__ void scatter_kernel(const int* __restrict__ ei,
                               int* __restrict__ cursor,
                               int* __restrict__ csr_src,
                               int* __restrict__ csr_dst) {
  int e = blockIdx.x * 256 + threadIdx.x;
  if (e < NEDGES) {
    int d = ei[NEDGES + e];
    int pos = atomicAdd(&cursor[d], 1);
    csr_src[pos] = ei[e];
    csr_dst[pos] = d;
  }
}

// ---------------------------------------------------------------------------
// Pass A: edge-parallel logits. One LANE per edge; serial dot over 448 ch.
// logits[e][0..6] = sum_c att[h][c] * lrelu(xl[src][h][c] + xr[dst][h][c])
// ---------------------------------------------------------------------------
__global__ __launch_bounds__(256) void edge_logits_kernel(
    const short* __restrict__ xlr, const float* __restrict__ att,
    const int* __restrict__ csr_src, const int* __restrict__ csr_dst,
    float* __restrict__ logits) {
  __shared__ float att_s[HC];
  for (int i = threadIdx.x; i < HC; i += 256) att_s[i] = att[i];
  __syncthreads();
  int e = blockIdx.x * 256 + threadIdx.x;
  if (e >= ETOT) return;
  int s = csr_src[e], d = csr_dst[e];
  const short* xlp = &xlr[(size_t)s * HC2];
  const short* xrp = &xlr[(size_t)d * HC2 + HC];
  float p[HEADS];
  #pragma unroll
  for (int h = 0; h < HEADS; ++h) p[h] = 0.f;
  for (int h = 0; h < HEADS; ++h) {
    float acc = 0.f;
    #pragma unroll
    for (int c8 = 0; c8 < 8; ++c8) {
      uint4 a = *(const uint4*)(xlp + h * 64 + c8 * 8);
      uint4 b = *(const uint4*)(xrp + h * 64 + c8 * 8);
      unsigned ua[4] = {a.x, a.y, a.z, a.w};
      unsigned ub[4] = {b.x, b.y, b.z, b.w};
      #pragma unroll
      for (int q = 0; q < 4; ++q) {
        float t0 = bf_lo(ua[q]) + bf_lo(ub[q]);
        t0 = fmaxf(t0, 0.2f * t0);
        acc += t0 * att_s[h * 64 + c8 * 8 + q * 2];
        float t1 = bf_hi(ua[q]) + bf_hi(ub[q]);
        t1 = fmaxf(t1, 0.2f * t1);
        acc += t1 * att_s[h * 64 + c8 * 8 + q * 2 + 1];
      }
    }
    p[h] = acc;
  }
  float4 o0 = {p[0], p[1], p[2], p[3]};
  float4 o1 = {p[4], p[5], p[6], 0.f};
  *(float4*)&logits[(size_t)e * 8] = o0;
  *(float4*)&logits[(size_t)e * 8 + 4] = o1;
}

// ---------------------------------------------------------------------------
// Pass B: per-dst softmax + weighted aggregation. Wave per node, lane = chan.
// ---------------------------------------------------------------------------
__global__ __launch_bounds__(256) void gat_agg2_kernel(
    const short* __restrict__ xlr, const float* __restrict__ logits,
    const float* __restrict__ cbias, const int* __restrict__ row_start,
    const int* __restrict__ csr_src, short* __restrict__ hout) {
  int lane = threadIdx.x & 63;
  int wid = threadIdx.x >> 6;
  int n = blockIdx.x * 4 + wid;
  if (n >= NNODES) return;
  int beg = row_start[n], end = row_start[n + 1];

  // stage 1: lanes 0..6 compute per-head max and sum-exp (exact softmax)
  float m = -1e30f, lsum = 0.f;
  if (lane < HEADS) {
    for (int e = beg; e < end; ++e)
      m = fmaxf(m, logits[(size_t)e * 8 + lane]);
    for (int e = beg; e < end; ++e)
      lsum += __expf(logits[(size_t)e * 8 + lane] - m);
  }
  float mh[HEADS], rl[HEADS];
  #pragma unroll
  for (int h = 0; h < HEADS; ++h) {
    mh[h] = __shfl(m, h, 64);
    rl[h] = __shfl(lsum, h, 64);
  }
  #pragma unroll
  for (int h = 0; h < HEADS; ++h) rl[h] = 1.0f / (rl[h] + 1e-16f);

  // stage 2: aggregate
  float out[HEADS];
  #pragma unroll
  for (int h = 0; h < HEADS; ++h) out[h] = 0.f;
  for (int e = beg; e < end; ++e) {
    int s = csr_src[e];
    float4 la = *(const float4*)&logits[(size_t)e * 8];
    float4 lb = *(const float4*)&logits[(size_t)e * 8 + 4];
    float al[HEADS];
    al[0] = __expf(la.x - mh[0]) * rl[0];
    al[1] = __expf(la.y - mh[1]) * rl[1];
    al[2] = __expf(la.z - mh[2]) * rl[2];
    al[3] = __expf(la.w - mh[3]) * rl[3];
    al[4] = __expf(lb.x - mh[4]) * rl[4];
    al[5] = __expf(lb.y - mh[5]) * rl[5];
    al[6] = __expf(lb.z - mh[6]) * rl[6];
    const unsigned short* xlp =
        (const unsigned short*)&xlr[(size_t)s * HC2 + lane];
    #pragma unroll
    for (int h = 0; h < HEADS; ++h)
      out[h] += al[h] * bf1(xlp[h * 64]);
  }

  float acc = 0.f;
  #pragma unroll
  for (int h = 0; h < HEADS; ++h) acc += out[h];
  float v = acc * (1.0f / 7.0f) + cbias[lane];
  hout[(size_t)n * 64 + lane] =
      __bfloat16_as_short(__float2bfloat16(fmaxf(v, 0.f)));
}

// ---------------------------------------------------------------------------
// Output MLP 64->32->16->9 + log_softmax, wave per node, 4 nodes per block.
// ---------------------------------------------------------------------------
__global__ __launch_bounds__(256) void out_mlp_kernel(
    const short* __restrict__ h, const float* __restrict__ V1,
    const float* __restrict__ c1, const float* __restrict__ V2,
    const float* __restrict__ c2, const float* __restrict__ V3,
    const float* __restrict__ c3, float* __restrict__ out) {
  __shared__ float hb[4][64], r1[4][32], r2[4][16], z3[4][9];
  int wid = threadIdx.x >> 6;
  int t = threadIdx.x & 63;
  int n = blockIdx.x * 4 + wid;
  hb[wid][t] = bf1(((const unsigned short*)h)[(size_t)n * 64 + t]);
  __syncthreads();
  if (t < 32) {
    float a = c1[t];
    #pragma unroll
    for (int k = 0; k < 64; ++k) a += hb[wid][k] * V1[k * 32 + t];
    r1[wid][t] = fmaxf(a, 0.f);
  }
  __syncthreads();
  if (t < 16) {
    float a = c2[t];
    #pragma unroll
    for (int k = 0; k < 32; ++k) a += r1[wid][k] * V2[k * 16 + t];
    r2[wid][t] = fmaxf(a, 0.f);
  }
  __syncthreads();
  if (t < 9) {
    float a = c3[t];
    #pragma unroll
    for (int k = 0; k < 16; ++k) a += r2[wid][k] * V3[k * 9 + t];
    z3[wid][t] = a;
  }
  __syncthreads();
  if (t < 9) {
    float mx = z3[wid][0];
    #pragma unroll
    for (int k = 1; k < 9; ++k) mx = fmaxf(mx, z3[wid][k]);
    float s = 0.f;
    #pragma unroll
    for (int k = 0; k < 9; ++k) s += __expf(z3[wid][k] - mx);
    out[(size_t)n * 9 + t] = z3[wid][t] - mx - logf(s);
  }
}

// ---------------------------------------------------------------------------
extern "C" void kernel_launch(void* const* d_in, const int* in_sizes, int n_in,
                              void* d_out, int out_size, void* d_ws, size_t ws_size,
                              hipStream_t stream) {
  const float* x   = (const float*)d_in[0];
  const int*   ei  = (const int*)d_in[1];
  const float* W1  = (const float*)d_in[2];
  const float* b1  = (const float*)d_in[3];
  const float* W2  = (const float*)d_in[4];
  const float* b2  = (const float*)d_in[5];
  const float* W3  = (const float*)d_in[6];
  const float* b3  = (const float*)d_in[7];
  const float* Wl  = (const float*)d_in[8];
  const float* bl  = (const float*)d_in[9];
  const float* Wr  = (const float*)d_in[10];
  const float* att = (const float*)d_in[11];
  const float* cb  = (const float*)d_in[12];
  const float* V1  = (const float*)d_in[13];
  const float* c1  = (const float*)d_in[14];
  const float* V2  = (const float*)d_in[15];
  const float* c2  = (const float*)d_in[16];
  const float* V3  = (const float*)d_in[17];
  const float* c3  = (const float*)d_in[18];
  float* out = (float*)d_out;

  char* ws = (char*)d_ws;
  size_t off = 0;
  auto alloc = [&](size_t bytes) {
    void* p = ws + off;
    off = (off + bytes + 255) & ~(size_t)255;
    return p;
  };
  // region0 (reused): xb (20.5MB) -> h2 -> xlr
  char* region0 = (char*)alloc((size_t)NNODES * 1024 * 2 + 1024);
  short* xb  = (short*)region0;
  short* h2  = (short*)region0;
  short* xlr = (short*)region0;
  // region1 (reused): h1 (10.2MB) -> hA/hB
  char* region1 = (char*)alloc((size_t)NNODES * 512 * 2 + 1024);
  short* h1 = (short*)region1;
  short* hA = (short*)region1;
  short* hB = hA + (size_t)NNODES * 64;
  // persistent
  short* W1t = (short*)alloc((size_t)512 * 1024 * 2);
  short* W2t = (short*)alloc((size_t)256 * 512 * 2);
  short* W3t = (short*)alloc((size_t)64 * 256 * 2);
  short* Wgt = (short*)alloc((size_t)5 * HC2 * 64 * 2);
  float* bg  = (float*)alloc((size_t)5 * HC2 * 4);
  int* cnt       = (int*)alloc((size_t)NNODES * 4);
  int* row_start = (int*)alloc((size_t)(NNODES + 1) * 4);
  int* cursor    = (int*)alloc((size_t)NNODES * 4);
  int* csr_src   = (int*)alloc((size_t)ETOT * 4);
  int* csr_dst   = (int*)alloc((size_t)ETOT * 4);
  float* logits  = (float*)alloc((size_t)ETOT * 8 * 4);

  // ---- pack / convert
  convert_f32_bf16<<<(NNODES * 1024 / 4 + 255) / 256, 256, 0, stream>>>(
      x, xb, NNODES * 1024 / 4);
  transpose_bf16<<<(1024 * 512 + 255) / 256, 256, 0, stream>>>(W1, W1t, 1024, 512);
  transpose_bf16<<<(512 * 256 + 255) / 256, 256, 0, stream>>>(W2, W2t, 512, 256);
  transpose_bf16<<<(256 * 64 + 255) / 256, 256, 0, stream>>>(W3, W3t, 256, 64);
  pack_gat<<<(5 * HC2 * 64 + 255) / 256, 256, 0, stream>>>(Wl, Wr, bl, Wgt, bg);

  // ---- CSR build (self-loops included)
  init_cnt<<<(NNODES + 255) / 256, 256, 0, stream>>>(cnt);
  hist_kernel<<<(NEDGES + 255) / 256, 256, 0, stream>>>(ei, cnt);
  scan_kernel<<<1, 1024, 0, stream>>>(cnt, row_start, cursor);
  scatter_self<<<(NNODES + 255) / 256, 256, 0, stream>>>(cursor, csr_src, csr_dst);
  scatter_kernel<<<(NEDGES + 255) / 256, 256, 0, stream>>>(ei, cursor, csr_src, csr_dst);

  // ---- input MLP (bf16 MFMA)
  mfma_gemm<1, 1><<<dim3(79, 4), 256, 0, stream>>>(xb, W1t, b1, h1, NNODES, 1024, 512);
  mfma_gemm<1, 1><<<dim3(79, 2), 256, 0, stream>>>(h1, W2t, b2, h2, NNODES, 512, 256);
  mfma_gemm<1, 1><<<dim3(79, 1), 256, 0, stream>>>(h2, W3t, b3, hA, NNODES, 256, 64);

  // ---- 5 GATv2 layers
  short* hcur = hA;
  short* hnext = hB;
  for (int layer = 0; layer < 5; ++layer) {
    mfma_gemm<1, 0><<<dim3(79, 7), 256, 0, stream>>>(
        hcur, Wgt + (size_t)layer * HC2 * 64, bg + (size_t)layer * HC2, xlr,
        NNODES, 64, HC2);
    edge_logits_kernel<<<(ETOT + 255) / 256, 256, 0, stream>>>(
        xlr, att + (size_t)layer * HC, csr_src, csr_dst, logits);
    gat_agg2_kernel<<<2500, 256, 0, stream>>>(
        xlr, logits, cb + (size_t)layer * 64, row_start, csr_src, hnext);
    short* tmp = hcur; hcur = hnext; hnext = tmp;
  }

  // ---- output MLP + log_softmax
  out_mlp_kernel<<<2500, 256, 0, stream>>>(hcur, V1, c1, V2, c2, V3, c3, out);
}

// Round 4
// 677.798 us; speedup vs baseline: 1.7027x; 1.1872x over previous
//
#include <hip/hip_runtime.h>
#include <hip/hip_bf16.h>
#include <math.h>

#define NNODES 10000
#define NEDGES 160000
#define ETOT (NEDGES + NNODES)  // edges + self-loops
#define HEADS 7
#define CH 64
#define HC 448   // HEADS*CH
#define HC2 896  // xl|xr fused

typedef __attribute__((ext_vector_type(8))) short short8;
typedef __attribute__((ext_vector_type(4))) float floatx4;

__device__ __forceinline__ float bf_lo(unsigned u) {
  return __uint_as_float(u << 16);
}
__device__ __forceinline__ float bf_hi(unsigned u) {
  return __uint_as_float(u & 0xffff0000u);
}

// ---------------------------------------------------------------------------
// Conversion / packing kernels
// ---------------------------------------------------------------------------
__global__ __launch_bounds__(256) void convert_f32_bf16(
    const float* __restrict__ in, short* __restrict__ out, int n4) {
  int i = blockIdx.x * 256 + threadIdx.x;
  if (i < n4) {
    float4 v = *(const float4*)&in[(size_t)i * 4];
    short4 o;
    o.x = __bfloat16_as_short(__float2bfloat16(v.x));
    o.y = __bfloat16_as_short(__float2bfloat16(v.y));
    o.z = __bfloat16_as_short(__float2bfloat16(v.z));
    o.w = __bfloat16_as_short(__float2bfloat16(v.w));
    *(short4*)&out[(size_t)i * 4] = o;
  }
}

__global__ __launch_bounds__(256) void transpose_bf16(
    const float* __restrict__ in, short* __restrict__ out, int K, int N) {
  int idx = blockIdx.x * 256 + threadIdx.x;
  if (idx < K * N) {
    int n = idx / K, k = idx % K;
    out[idx] = __bfloat16_as_short(__float2bfloat16(in[(size_t)k * N + n]));
  }
}

__global__ __launch_bounds__(256) void pack_gat(
    const float* __restrict__ Wl, const float* __restrict__ Wr,
    const float* __restrict__ bl, short* __restrict__ Wgt,
    float* __restrict__ bg) {
  int idx = blockIdx.x * 256 + threadIdx.x;
  if (idx < 5 * HC2 * 64) {
    int l = idx / (HC2 * 64);
    int rem = idx % (HC2 * 64);
    int n = rem / 64, k = rem % 64;
    float v = (n < HC) ? Wl[((size_t)l * 64 + k) * HC + n]
                       : Wr[((size_t)l * 64 + k) * HC + (n - HC)];
    Wgt[idx] = __bfloat16_as_short(__float2bfloat16(v));
  }
  if (idx < 5 * HC2) {
    int l = idx / HC2, n = idx % HC2;
    bg[idx] = (n < HC) ? bl[(size_t)l * HC + n] : 0.f;
  }
}

// ---------------------------------------------------------------------------
// MFMA bf16 GEMM: C = act(A @ Bt^T + bias)
// MODE 1: C bf16 [M,Nc] row-major.  MODE 2: GAT-t layout xlt[n][c][8]:
//   col<448 -> slot c*8+h; col>=448 -> slot 512+c*8+h (row stride 1024 shorts)
// ---------------------------------------------------------------------------
__device__ __forceinline__ void stage_tile(
    const short* __restrict__ g, int rows_total, int K, int row0, int k0,
    short* lds, int wave, int lane) {
  #pragma unroll
  for (int i = 0; i < 4; ++i) {
    int c = i * 4 + wave;
    int r = c * 8 + (lane >> 3);
    int k = (lane & 7) * 8;
    int grow = row0 + r;
    if (grow >= rows_total) grow = rows_total - 1;
    const short* gp = g + (size_t)grow * K + k0 + k;
    short* lp = lds + c * 512;
    __builtin_amdgcn_global_load_lds(
        (const __attribute__((address_space(1))) void*)gp,
        (__attribute__((address_space(3))) void*)lp, 16, 0, 0);
  }
}

template <int MODE, int RELU>
__global__ __launch_bounds__(256) void mfma_gemm(
    const short* __restrict__ A, const short* __restrict__ Bt,
    const float* __restrict__ bias, void* __restrict__ C,
    int M, int K, int Nc) {
  __shared__ short As[128 * 64];
  __shared__ short Bs[128 * 64];
  int tid = threadIdx.x;
  int lane = tid & 63, wave = tid >> 6;
  int wm = wave >> 1, wn = wave & 1;
  int row0 = blockIdx.x * 128, col0 = blockIdx.y * 128;
  floatx4 acc[4][4] = {};

  for (int k0 = 0; k0 < K; k0 += 64) {
    stage_tile(A, M, K, row0, k0, As, wave, lane);
    stage_tile(Bt, Nc, K, col0, k0, Bs, wave, lane);
    __syncthreads();
    int lr = lane & 15, lq = lane >> 4;
    #pragma unroll
    for (int kk = 0; kk < 64; kk += 32) {
      short8 af[4], bf[4];
      #pragma unroll
      for (int i = 0; i < 4; ++i)
        af[i] = *(const short8*)&As[(wm * 64 + i * 16 + lr) * 64 + kk + lq * 8];
      #pragma unroll
      for (int j = 0; j < 4; ++j)
        bf[j] = *(const short8*)&Bs[(wn * 64 + j * 16 + lr) * 64 + kk + lq * 8];
      #pragma unroll
      for (int i = 0; i < 4; ++i)
        #pragma unroll
        for (int j = 0; j < 4; ++j)
          acc[i][j] = __builtin_amdgcn_mfma_f32_16x16x32_bf16(
              af[i], bf[j], acc[i][j], 0, 0, 0);
    }
    __syncthreads();
  }

  int lr = lane & 15, lq = lane >> 4;
  #pragma unroll
  for (int j = 0; j < 4; ++j) {
    int col = col0 + wn * 64 + j * 16 + lr;
    if (col >= Nc) continue;
    float bj = bias ? bias[col] : 0.f;
    size_t tpos = 0;
    if (MODE == 2) {
      int half = (col >= HC);
      int h = (col - (half ? HC : 0)) >> 6;
      int c = col & 63;
      tpos = (size_t)(half * 512 + c * 8 + h);
    }
    #pragma unroll
    for (int i = 0; i < 4; ++i) {
      int rbase = row0 + wm * 64 + i * 16 + lq * 4;
      #pragma unroll
      for (int r = 0; r < 4; ++r) {
        int row = rbase + r;
        if (row < M) {
          float v = acc[i][j][r] + bj;
          if (RELU) v = fmaxf(v, 0.f);
          if (MODE == 2)
            ((unsigned short*)C)[(size_t)row * 1024 + tpos] =
                (unsigned short)__bfloat16_as_short(__float2bfloat16(v));
          else
            ((__hip_bfloat16*)C)[(size_t)row * Nc + col] = __float2bfloat16(v);
        }
      }
    }
  }
}

// ---------------------------------------------------------------------------
// CSR build (dst-grouped, self-loops included).
// ---------------------------------------------------------------------------
__global__ void init_cnt(int* __restrict__ cnt) {
  int i = blockIdx.x * 256 + threadIdx.x;
  if (i < NNODES) cnt[i] = 1;  // self-loop
}

__global__ void hist_kernel(const int* __restrict__ ei, int* __restrict__ cnt) {
  int e = blockIdx.x * 256 + threadIdx.x;
  if (e < NEDGES) atomicAdd(&cnt[ei[NEDGES + e]], 1);
}

// single-block shuffle-based scan: each thread 10 elems, wave scan, LDS combine
__global__ __launch_bounds__(1024) void scan_kernel(
    const int* __restrict__ cnt, int* __restrict__ row_start,
    int* __restrict__ cursor) {
  __shared__ int wsum[16];
  int t = threadIdx.x;
  int lane = t & 63, w = t >> 6;
  int base = t * 10;
  int v[10], s = 0;
  #pragma unroll
  for (int i = 0; i < 10; ++i) {
    v[i] = (base + i < NNODES) ? cnt[base + i] : 0;
    s += v[i];
  }
  int incl = s;
  #pragma unroll
  for (int off = 1; off < 64; off <<= 1) {
    int o = __shfl_up(incl, off, 64);
    if (lane >= off) incl += o;
  }
  if (lane == 63) wsum[w] = incl;
  __syncthreads();
  if (w == 0) {
    int wv = (lane < 16) ? wsum[lane] : 0;
    #pragma unroll
    for (int off = 1; off < 16; off <<= 1) {
      int o = __shfl_up(wv, off, 64);
      if (lane >= off) wv += o;
    }
    if (lane < 16) wsum[lane] = wv;
  }
  __syncthreads();
  int woff = (w > 0) ? wsum[w - 1] : 0;
  int excl = woff + incl - s;
  #pragma unroll
  for (int i = 0; i < 10; ++i) {
    if (base + i < NNODES) {
      row_start[base + i] = excl;
      cursor[base + i] = excl;
    }
    excl += v[i];
  }
  if (t == 1023) row_start[NNODES] = wsum[15];
}

__global__ void scatter_self(int* __restrict__ cursor,
                             int* __restrict__ csr_src,
                             int* __restrict__ csr_dst) {
  int n = blockIdx.x * 256 + threadIdx.x;
  if (n < NNODES) {
    int pos = atomicAdd(&cursor[n], 1);
    csr_src[pos] = n;
    csr_dst[pos] = n;
  }
}

__global__ void scatter_kernel(const int* __restrict__ ei,
                               int* __restrict__ cursor,
                               int* __restrict__ csr_src,
                               int* __restrict__ csr_dst) {
  int e = blockIdx.x * 256 + threadIdx.x;
  if (e < NEDGES) {
    int d = ei[NEDGES + e];
    int pos = atomicAdd(&cursor[d], 1);
    csr_src[pos] = ei[e];
    csr_dst[pos] = d;
  }
}

// ---------------------------------------------------------------------------
// Pass A: edge logits, 8 lanes per edge on xlt[n][c][8] layout.
// lane = eo*8+cl; lane cl covers channels {cl, cl+8, ..., cl+56}.
// ---------------------------------------------------------------------------
__global__ __launch_bounds__(256) void edge_logits_kernel(
    const short* __restrict__ xlt, const float* __restrict__ att,
    const int* __restrict__ csr_src, const int* __restrict__ csr_dst,
    float* __restrict__ logits) {
  __shared__ float att_s[512];  // att_t[c][h]
  for (int i = threadIdx.x; i < 512; i += 256) {
    int c = i >> 3, h = i & 7;
    att_s[i] = (h < 7) ? att[h * 64 + c] : 0.f;
  }
  __syncthreads();
  int lane = threadIdx.x & 63;
  int wid = threadIdx.x >> 6;
  int eo = lane >> 3, cl = lane & 7;
  int e = (blockIdx.x * 4 + wid) * 8 + eo;
  int ec = (e < ETOT) ? e : (ETOT - 1);
  int s = csr_src[ec], d = csr_dst[ec];
  const uint4* xlp = (const uint4*)(xlt + (size_t)s * 1024);
  const uint4* xrp = (const uint4*)(xlt + (size_t)d * 1024 + 512);
  float acc[7];
  #pragma unroll
  for (int h = 0; h < 7; ++h) acc[h] = 0.f;
  #pragma unroll
  for (int q = 0; q < 8; ++q) {
    int c = q * 8 + cl;
    uint4 a = xlp[c];
    uint4 b = xrp[c];
    float4 t0 = *(const float4*)&att_s[c * 8];
    float4 t1 = *(const float4*)&att_s[c * 8 + 4];
    float e0 = bf_lo(a.x) + bf_lo(b.x);
    float e1 = bf_hi(a.x) + bf_hi(b.x);
    float e2 = bf_lo(a.y) + bf_lo(b.y);
    float e3 = bf_hi(a.y) + bf_hi(b.y);
    float e4 = bf_lo(a.z) + bf_lo(b.z);
    float e5 = bf_hi(a.z) + bf_hi(b.z);
    float e6 = bf_lo(a.w) + bf_lo(b.w);
    e0 = fmaxf(e0, 0.2f * e0); e1 = fmaxf(e1, 0.2f * e1);
    e2 = fmaxf(e2, 0.2f * e2); e3 = fmaxf(e3, 0.2f * e3);
    e4 = fmaxf(e4, 0.2f * e4); e5 = fmaxf(e5, 0.2f * e5);
    e6 = fmaxf(e6, 0.2f * e6);
    acc[0] += t0.x * e0; acc[1] += t0.y * e1;
    acc[2] += t0.z * e2; acc[3] += t0.w * e3;
    acc[4] += t1.x * e4; acc[5] += t1.y * e5;
    acc[6] += t1.z * e6;
  }
  #pragma unroll
  for (int h = 0; h < 7; ++h) {
    acc[h] += __shfl_xor(acc[h], 1, 64);
    acc[h] += __shfl_xor(acc[h], 2, 64);
    acc[h] += __shfl_xor(acc[h], 4, 64);
  }
  float res = 0.f;
  #pragma unroll
  for (int h = 0; h < 7; ++h) res = (cl == h) ? acc[h] : res;
  if (e < ETOT) logits[(size_t)e * 8 + cl] = res;  // wave: 256B coalesced
}

// ---------------------------------------------------------------------------
// Pass B: per-dst softmax + aggregation. Wave per node, lane = channel.
// ---------------------------------------------------------------------------
__global__ __launch_bounds__(256) void gat_agg2_kernel(
    const short* __restrict__ xlt, const float* __restrict__ logits,
    const float* __restrict__ cbias, const int* __restrict__ row_start,
    const int* __restrict__ csr_src, short* __restrict__ hout) {
  int lane = threadIdx.x & 63;
  int wid = threadIdx.x >> 6;
  int n = blockIdx.x * 4 + wid;
  if (n >= NNODES) return;
  int beg = row_start[n], end = row_start[n + 1];

  // stage 1: all-lane online softmax stats; lane = (eo, hm)
  int eo = lane >> 3, hm = lane & 7;
  float m = -1e30f, ssum = 0.f;
  for (int e = beg + eo; e < end; e += 8) {
    float lg = logits[(size_t)e * 8 + hm];  // wave: 256B coalesced
    float nm = fmaxf(m, lg);
    ssum = ssum * __expf(m - nm) + __expf(lg - nm);
    m = nm;
  }
  #pragma unroll
  for (int st = 8; st <= 32; st <<= 1) {
    float om = __shfl_xor(m, st, 64);
    float os = __shfl_xor(ssum, st, 64);
    float nm = fmaxf(m, om);
    ssum = ssum * __expf(m - nm) + os * __expf(om - nm);
    m = nm;
  }
  float mh[7], rl[7];
  #pragma unroll
  for (int h = 0; h < 7; ++h) {
    mh[h] = __shfl(m, h, 64);
    rl[h] = 1.0f / (__shfl(ssum, h, 64) + 1e-16f);
  }

  // stage 2: weighted aggregation; one 16B gather per edge per lane
  float o0 = 0.f, o1 = 0.f, o2 = 0.f, o3 = 0.f, o4 = 0.f, o5 = 0.f, o6 = 0.f;
  #pragma unroll 2
  for (int e = beg; e < end; ++e) {
    int s = csr_src[e];
    float4 la = *(const float4*)&logits[(size_t)e * 8];      // uniform
    float4 lb = *(const float4*)&logits[(size_t)e * 8 + 4];  // uniform
    uint4 xv = *(const uint4*)(xlt + (size_t)s * 1024 + lane * 8);
    float a0 = __expf(la.x - mh[0]) * rl[0];
    float a1 = __expf(la.y - mh[1]) * rl[1];
    float a2 = __expf(la.z - mh[2]) * rl[2];
    float a3 = __expf(la.w - mh[3]) * rl[3];
    float a4 = __expf(lb.x - mh[4]) * rl[4];
    float a5 = __expf(lb.y - mh[5]) * rl[5];
    float a6 = __expf(lb.z - mh[6]) * rl[6];
    o0 += a0 * bf_lo(xv.x);
    o1 += a1 * bf_hi(xv.x);
    o2 += a2 * bf_lo(xv.y);
    o3 += a3 * bf_hi(xv.y);
    o4 += a4 * bf_lo(xv.z);
    o5 += a5 * bf_hi(xv.z);
    o6 += a6 * bf_lo(xv.w);
  }

  float accv = o0 + o1 + o2 + o3 + o4 + o5 + o6;
  float v = accv * (1.0f / 7.0f) + cbias[lane];
  hout[(size_t)n * 64 + lane] =
      __bfloat16_as_short(__float2bfloat16(fmaxf(v, 0.f)));
}

// ---------------------------------------------------------------------------
// Output MLP 64->32->16->9 + log_softmax, wave per node, 4 nodes per block.
// ---------------------------------------------------------------------------
__global__ __launch_bounds__(256) void out_mlp_kernel(
    const short* __restrict__ h, const float* __restrict__ V1,
    const float* __restrict__ c1, const float* __restrict__ V2,
    const float* __restrict__ c2, const float* __restrict__ V3,
    const float* __restrict__ c3, float* __restrict__ out) {
  __shared__ float hb[4][64], r1[4][32], r2[4][16], z3[4][9];
  int wid = threadIdx.x >> 6;
  int t = threadIdx.x & 63;
  int n = blockIdx.x * 4 + wid;
  hb[wid][t] = bf_lo((unsigned)((const unsigned short*)h)[(size_t)n * 64 + t] << 0)
               * 0.f + __uint_as_float(((unsigned)((const unsigned short*)h)[(size_t)n * 64 + t]) << 16);
  __syncthreads();
  if (t < 32) {
    float a = c1[t];
    #pragma unroll
    for (int k = 0; k < 64; ++k) a += hb[wid][k] * V1[k * 32 + t];
    r1[wid][t] = fmaxf(a, 0.f);
  }
  __syncthreads();
  if (t < 16) {
    float a = c2[t];
    #pragma unroll
    for (int k = 0; k < 32; ++k) a += r1[wid][k] * V2[k * 16 + t];
    r2[wid][t] = fmaxf(a, 0.f);
  }
  __syncthreads();
  if (t < 9) {
    float a = c3[t];
    #pragma unroll
    for (int k = 0; k < 16; ++k) a += r2[wid][k] * V3[k * 9 + t];
    z3[wid][t] = a;
  }
  __syncthreads();
  if (t < 9) {
    float mx = z3[wid][0];
    #pragma unroll
    for (int k = 1; k < 9; ++k) mx = fmaxf(mx, z3[wid][k]);
    float s = 0.f;
    #pragma unroll
    for (int k = 0; k < 9; ++k) s += __expf(z3[wid][k] - mx);
    out[(size_t)n * 9 + t] = z3[wid][t] - mx - logf(s);
  }
}

// ---------------------------------------------------------------------------
extern "C" void kernel_launch(void* const* d_in, const int* in_sizes, int n_in,
                              void* d_out, int out_size, void* d_ws, size_t ws_size,
                              hipStream_t stream) {
  const float* x   = (const float*)d_in[0];
  const int*   ei  = (const int*)d_in[1];
  const float* W1  = (const float*)d_in[2];
  const float* b1  = (const float*)d_in[3];
  const float* W2  = (const float*)d_in[4];
  const float* b2  = (const float*)d_in[5];
  const float* W3  = (const float*)d_in[6];
  const float* b3  = (const float*)d_in[7];
  const float* Wl  = (const float*)d_in[8];
  const float* bl  = (const float*)d_in[9];
  const float* Wr  = (const float*)d_in[10];
  const float* att = (const float*)d_in[11];
  const float* cb  = (const float*)d_in[12];
  const float* V1  = (const float*)d_in[13];
  const float* c1  = (const float*)d_in[14];
  const float* V2  = (const float*)d_in[15];
  const float* c2  = (const float*)d_in[16];
  const float* V3  = (const float*)d_in[17];
  const float* c3  = (const float*)d_in[18];
  float* out = (float*)d_out;

  char* ws = (char*)d_ws;
  size_t off = 0;
  auto alloc = [&](size_t bytes) {
    void* p = ws + off;
    off = (off + bytes + 255) & ~(size_t)255;
    return p;
  };
  // region0 (reused): xb (20.5MB) -> h2 -> xlt [N][1024] shorts (20.5MB)
  char* region0 = (char*)alloc((size_t)NNODES * 1024 * 2 + 1024);
  short* xb  = (short*)region0;
  short* h2  = (short*)region0;
  short* xlt = (short*)region0;
  // region1 (reused): h1 (10.2MB) -> hA/hB
  char* region1 = (char*)alloc((size_t)NNODES * 512 * 2 + 1024);
  short* h1 = (short*)region1;
  short* hA = (short*)region1;
  short* hB = hA + (size_t)NNODES * 64;
  // persistent
  short* W1t = (short*)alloc((size_t)512 * 1024 * 2);
  short* W2t = (short*)alloc((size_t)256 * 512 * 2);
  short* W3t = (short*)alloc((size_t)64 * 256 * 2);
  short* Wgt = (short*)alloc((size_t)5 * HC2 * 64 * 2);
  float* bg  = (float*)alloc((size_t)5 * HC2 * 4);
  int* cnt       = (int*)alloc((size_t)NNODES * 4);
  int* row_start = (int*)alloc((size_t)(NNODES + 1) * 4);
  int* cursor    = (int*)alloc((size_t)NNODES * 4);
  int* csr_src   = (int*)alloc((size_t)ETOT * 4);
  int* csr_dst   = (int*)alloc((size_t)ETOT * 4);
  float* logits  = (float*)alloc((size_t)ETOT * 8 * 4);

  // ---- pack / convert
  convert_f32_bf16<<<(NNODES * 1024 / 4 + 255) / 256, 256, 0, stream>>>(
      x, xb, NNODES * 1024 / 4);
  transpose_bf16<<<(1024 * 512 + 255) / 256, 256, 0, stream>>>(W1, W1t, 1024, 512);
  transpose_bf16<<<(512 * 256 + 255) / 256, 256, 0, stream>>>(W2, W2t, 512, 256);
  transpose_bf16<<<(256 * 64 + 255) / 256, 256, 0, stream>>>(W3, W3t, 256, 64);
  pack_gat<<<(5 * HC2 * 64 + 255) / 256, 256, 0, stream>>>(Wl, Wr, bl, Wgt, bg);

  // ---- CSR build (self-loops included)
  init_cnt<<<(NNODES + 255) / 256, 256, 0, stream>>>(cnt);
  hist_kernel<<<(NEDGES + 255) / 256, 256, 0, stream>>>(ei, cnt);
  scan_kernel<<<1, 1024, 0, stream>>>(cnt, row_start, cursor);
  scatter_self<<<(NNODES + 255) / 256, 256, 0, stream>>>(cursor, csr_src, csr_dst);
  scatter_kernel<<<(NEDGES + 255) / 256, 256, 0, stream>>>(ei, cursor, csr_src, csr_dst);

  // ---- input MLP (bf16 MFMA)
  mfma_gemm<1, 1><<<dim3(79, 4), 256, 0, stream>>>(xb, W1t, b1, h1, NNODES, 1024, 512);
  mfma_gemm<1, 1><<<dim3(79, 2), 256, 0, stream>>>(h1, W2t, b2, h2, NNODES, 512, 256);
  mfma_gemm<1, 1><<<dim3(79, 1), 256, 0, stream>>>(h2, W3t, b3, hA, NNODES, 256, 64);

  // ---- 5 GATv2 layers
  short* hcur = hA;
  short* hnext = hB;
  for (int layer = 0; layer < 5; ++layer) {
    mfma_gemm<2, 0><<<dim3(79, 7), 256, 0, stream>>>(
        hcur, Wgt + (size_t)layer * HC2 * 64, bg + (size_t)layer * HC2, xlt,
        NNODES, 64, HC2);
    edge_logits_kernel<<<(ETOT + 31) / 32, 256, 0, stream>>>(
        xlt, att + (size_t)layer * HC, csr_src, csr_dst, logits);
    gat_agg2_kernel<<<2500, 256, 0, stream>>>(
        xlt, logits, cb + (size_t)layer * 64, row_start, csr_src, hnext);
    short* tmp = hcur; hcur = hnext; hnext = tmp;
  }

  // ---- output MLP + log_softmax
  out_mlp_kernel<<<2500, 256, 0, stream>>>(hcur, V1, c1, V2, c2, V3, c3, out);
}

// Round 5
// 576.041 us; speedup vs baseline: 2.0035x; 1.1766x over previous
//
#include <hip/hip_runtime.h>
#include <hip/hip_bf16.h>
#include <math.h>

#define NNODES 10000
#define NEDGES 160000
#define ETOT (NEDGES + NNODES)  // edges + self-loops
#define HEADS 7
#define CH 64
#define HC 448    // HEADS*CH
#define HCP 1024  // padded fused width: [xl 512 | xr 512], slot = half*512+c*8+h

typedef __attribute__((ext_vector_type(8))) short short8;
typedef __attribute__((ext_vector_type(4))) float floatx4;

__device__ __forceinline__ float bf_lo(unsigned u) {
  return __uint_as_float(u << 16);
}
__device__ __forceinline__ float bf_hi(unsigned u) {
  return __uint_as_float(u & 0xffff0000u);
}

// ---------------------------------------------------------------------------
// Conversion / packing kernels
// ---------------------------------------------------------------------------
__global__ __launch_bounds__(256) void convert_f32_bf16(
    const float* __restrict__ in, short* __restrict__ out, int n4) {
  int i = blockIdx.x * 256 + threadIdx.x;
  if (i < n4) {
    float4 v = *(const float4*)&in[(size_t)i * 4];
    short4 o;
    o.x = __bfloat16_as_short(__float2bfloat16(v.x));
    o.y = __bfloat16_as_short(__float2bfloat16(v.y));
    o.z = __bfloat16_as_short(__float2bfloat16(v.z));
    o.w = __bfloat16_as_short(__float2bfloat16(v.w));
    *(short4*)&out[(size_t)i * 4] = o;
  }
}

__global__ __launch_bounds__(256) void transpose_bf16(
    const float* __restrict__ in, short* __restrict__ out, int K, int N) {
  int idx = blockIdx.x * 256 + threadIdx.x;
  if (idx < K * N) {
    int n = idx / K, k = idx % K;
    out[idx] = __bfloat16_as_short(__float2bfloat16(in[(size_t)k * N + n]));
  }
}

// Wgt[l][col'][k], col' = half*512 + c*8 + h (h==7 -> zero pad). bg likewise.
__global__ __launch_bounds__(256) void pack_gat(
    const float* __restrict__ Wl, const float* __restrict__ Wr,
    const float* __restrict__ bl, short* __restrict__ Wgt,
    float* __restrict__ bg) {
  int idx = blockIdx.x * 256 + threadIdx.x;
  if (idx < 5 * HCP * 64) {
    int l = idx / (HCP * 64);
    int rem = idx % (HCP * 64);
    int col = rem / 64, k = rem % 64;
    int half = col >> 9;
    int within = col & 511;
    int c = within >> 3, h = within & 7;
    float v = 0.f;
    if (h < 7) {
      const float* W = half ? Wr : Wl;
      v = W[((size_t)l * 64 + k) * HC + h * 64 + c];
    }
    Wgt[idx] = __bfloat16_as_short(__float2bfloat16(v));
  }
  if (idx < 5 * HCP) {
    int l = idx >> 10, col = idx & 1023;
    int half = col >> 9, within = col & 511;
    int c = within >> 3, h = within & 7;
    bg[idx] = (!half && h < 7) ? bl[(size_t)l * HC + h * 64 + c] : 0.f;
  }
}

// ---------------------------------------------------------------------------
// MFMA bf16 GEMM: C = act(A @ Bt^T + bias), bf16 row-major out.
// A:[M,K] bf16, Bt:[Nc,K] bf16. Tile BMxBN, BK=64, 256 thr (2x2 waves).
// ---------------------------------------------------------------------------
template <int BM, int BN, int RELU>
__global__ __launch_bounds__(256) void mfma_gemm(
    const short* __restrict__ A, const short* __restrict__ Bt,
    const float* __restrict__ bias, short* __restrict__ C,
    int M, int K, int Nc) {
  __shared__ short As[BM * 64];
  __shared__ short Bs[BN * 64];
  constexpr int MI = BM / 32;  // 16-row tiles per wave
  constexpr int NJ = BN / 32;
  int tid = threadIdx.x;
  int lane = tid & 63, wave = tid >> 6;
  int wm = wave >> 1, wn = wave & 1;
  int row0 = blockIdx.x * BM, col0 = blockIdx.y * BN;
  floatx4 acc[MI][NJ] = {};

  for (int k0 = 0; k0 < K; k0 += 64) {
    #pragma unroll
    for (int i = 0; i < BM / 32; ++i) {
      int c = i * 4 + wave;
      int r = c * 8 + (lane >> 3);
      int k = (lane & 7) * 8;
      int grow = row0 + r;
      if (grow >= M) grow = M - 1;
      __builtin_amdgcn_global_load_lds(
          (const __attribute__((address_space(1))) void*)(A + (size_t)grow * K + k0 + k),
          (__attribute__((address_space(3))) void*)(As + c * 512), 16, 0, 0);
    }
    #pragma unroll
    for (int i = 0; i < BN / 32; ++i) {
      int c = i * 4 + wave;
      int r = c * 8 + (lane >> 3);
      int k = (lane & 7) * 8;
      int gcol = col0 + r;
      if (gcol >= Nc) gcol = Nc - 1;
      __builtin_amdgcn_global_load_lds(
          (const __attribute__((address_space(1))) void*)(Bt + (size_t)gcol * K + k0 + k),
          (__attribute__((address_space(3))) void*)(Bs + c * 512), 16, 0, 0);
    }
    __syncthreads();
    int lr = lane & 15, lq = lane >> 4;
    #pragma unroll
    for (int kk = 0; kk < 64; kk += 32) {
      short8 af[MI], bf[NJ];
      #pragma unroll
      for (int i = 0; i < MI; ++i)
        af[i] = *(const short8*)&As[(wm * (BM / 2) + i * 16 + lr) * 64 + kk + lq * 8];
      #pragma unroll
      for (int j = 0; j < NJ; ++j)
        bf[j] = *(const short8*)&Bs[(wn * (BN / 2) + j * 16 + lr) * 64 + kk + lq * 8];
      #pragma unroll
      for (int i = 0; i < MI; ++i)
        #pragma unroll
        for (int j = 0; j < NJ; ++j)
          acc[i][j] = __builtin_amdgcn_mfma_f32_16x16x32_bf16(
              af[i], bf[j], acc[i][j], 0, 0, 0);
    }
    __syncthreads();
  }

  int lr = lane & 15, lq = lane >> 4;
  #pragma unroll
  for (int j = 0; j < NJ; ++j) {
    int col = col0 + wn * (BN / 2) + j * 16 + lr;
    float bj = bias ? bias[col] : 0.f;
    #pragma unroll
    for (int i = 0; i < MI; ++i) {
      int rbase = row0 + wm * (BM / 2) + i * 16 + lq * 4;
      #pragma unroll
      for (int r = 0; r < 4; ++r) {
        int row = rbase + r;
        if (row < M) {
          float v = acc[i][j][r] + bj;
          if (RELU) v = fmaxf(v, 0.f);
          C[(size_t)row * Nc + col] = __bfloat16_as_short(__float2bfloat16(v));
        }
      }
    }
  }
}

// ---------------------------------------------------------------------------
// CSR build (dst-grouped, self-loops included).
// ---------------------------------------------------------------------------
__global__ void init_cnt(int* __restrict__ cnt) {
  int i = blockIdx.x * 256 + threadIdx.x;
  if (i < NNODES) cnt[i] = 1;  // self-loop
}

__global__ void hist_kernel(const int* __restrict__ ei, int* __restrict__ cnt) {
  int e = blockIdx.x * 256 + threadIdx.x;
  if (e < NEDGES) atomicAdd(&cnt[ei[NEDGES + e]], 1);
}

// single-block shuffle-based scan
__global__ __launch_bounds__(1024) void scan_kernel(
    const int* __restrict__ cnt, int* __restrict__ row_start,
    int* __restrict__ cursor) {
  __shared__ int wsum[16];
  int t = threadIdx.x;
  int lane = t & 63, w = t >> 6;
  int base = t * 10;
  int v[10], s = 0;
  #pragma unroll
  for (int i = 0; i < 10; ++i) {
    v[i] = (base + i < NNODES) ? cnt[base + i] : 0;
    s += v[i];
  }
  int incl = s;
  #pragma unroll
  for (int off = 1; off < 64; off <<= 1) {
    int o = __shfl_up(incl, off, 64);
    if (lane >= off) incl += o;
  }
  if (lane == 63) wsum[w] = incl;
  __syncthreads();
  if (w == 0) {
    int wv = (lane < 16) ? wsum[lane] : 0;
    #pragma unroll
    for (int off = 1; off < 16; off <<= 1) {
      int o = __shfl_up(wv, off, 64);
      if (lane >= off) wv += o;
    }
    if (lane < 16) wsum[lane] = wv;
  }
  __syncthreads();
  int woff = (w > 0) ? wsum[w - 1] : 0;
  int excl = woff + incl - s;
  #pragma unroll
  for (int i = 0; i < 10; ++i) {
    if (base + i < NNODES) {
      row_start[base + i] = excl;
      cursor[base + i] = excl;
    }
    excl += v[i];
  }
  if (t == 1023) row_start[NNODES] = wsum[15];
}

__global__ void scatter_self(int* __restrict__ cursor,
                             int* __restrict__ csr_src,
                             int* __restrict__ csr_dst) {
  int n = blockIdx.x * 256 + threadIdx.x;
  if (n < NNODES) {
    int pos = atomicAdd(&cursor[n], 1);
    csr_src[pos] = n;
    csr_dst[pos] = n;
  }
}

__global__ void scatter_kernel(const int* __restrict__ ei,
                               int* __restrict__ cursor,
                               int* __restrict__ csr_src,
                               int* __restrict__ csr_dst) {
  int e = blockIdx.x * 256 + threadIdx.x;
  if (e < NEDGES) {
    int d = ei[NEDGES + e];
    int pos = atomicAdd(&cursor[d], 1);
    csr_src[pos] = ei[e];
    csr_dst[pos] = d;
  }
}

// ---------------------------------------------------------------------------
// Pass A: edge logits, 8 lanes per edge on xlt[n][c][8] layout.
// ---------------------------------------------------------------------------
__global__ __launch_bounds__(256) void edge_logits_kernel(
    const short* __restrict__ xlt, const float* __restrict__ att,
    const int* __restrict__ csr_src, const int* __restrict__ csr_dst,
    float* __restrict__ logits) {
  __shared__ float att_s[512];  // att_t[c][h]
  for (int i = threadIdx.x; i < 512; i += 256) {
    int c = i >> 3, h = i & 7;
    att_s[i] = (h < 7) ? att[h * 64 + c] : 0.f;
  }
  __syncthreads();
  int lane = threadIdx.x & 63;
  int wid = threadIdx.x >> 6;
  int eo = lane >> 3, cl = lane & 7;
  int e = (blockIdx.x * 4 + wid) * 8 + eo;
  int ec = (e < ETOT) ? e : (ETOT - 1);
  int s = csr_src[ec], d = csr_dst[ec];
  const uint4* xlp = (const uint4*)(xlt + (size_t)s * HCP);
  const uint4* xrp = (const uint4*)(xlt + (size_t)d * HCP + 512);
  float acc[7];
  #pragma unroll
  for (int h = 0; h < 7; ++h) acc[h] = 0.f;
  #pragma unroll
  for (int q = 0; q < 8; ++q) {
    int c = q * 8 + cl;
    uint4 a = xlp[c];
    uint4 b = xrp[c];
    float4 t0 = *(const float4*)&att_s[c * 8];
    float4 t1 = *(const float4*)&att_s[c * 8 + 4];
    float e0 = bf_lo(a.x) + bf_lo(b.x);
    float e1 = bf_hi(a.x) + bf_hi(b.x);
    float e2 = bf_lo(a.y) + bf_lo(b.y);
    float e3 = bf_hi(a.y) + bf_hi(b.y);
    float e4 = bf_lo(a.z) + bf_lo(b.z);
    float e5 = bf_hi(a.z) + bf_hi(b.z);
    float e6 = bf_lo(a.w) + bf_lo(b.w);
    e0 = fmaxf(e0, 0.2f * e0); e1 = fmaxf(e1, 0.2f * e1);
    e2 = fmaxf(e2, 0.2f * e2); e3 = fmaxf(e3, 0.2f * e3);
    e4 = fmaxf(e4, 0.2f * e4); e5 = fmaxf(e5, 0.2f * e5);
    e6 = fmaxf(e6, 0.2f * e6);
    acc[0] += t0.x * e0; acc[1] += t0.y * e1;
    acc[2] += t0.z * e2; acc[3] += t0.w * e3;
    acc[4] += t1.x * e4; acc[5] += t1.y * e5;
    acc[6] += t1.z * e6;
  }
  #pragma unroll
  for (int h = 0; h < 7; ++h) {
    acc[h] += __shfl_xor(acc[h], 1, 64);
    acc[h] += __shfl_xor(acc[h], 2, 64);
    acc[h] += __shfl_xor(acc[h], 4, 64);
  }
  float res = 0.f;
  #pragma unroll
  for (int h = 0; h < 7; ++h) res = (cl == h) ? acc[h] : res;
  if (e < ETOT) logits[(size_t)e * 8 + cl] = res;  // 256B coalesced per wave
}

// ---------------------------------------------------------------------------
// Pass B: per-dst softmax + aggregation. Wave per node, lane = channel.
// Alphas computed once per (edge,head) by lane (eo,hm), shared via LDS
// (same-wave DS ops are in-order; no barrier needed).
// ---------------------------------------------------------------------------
__global__ __launch_bounds__(256) void gat_agg2_kernel(
    const short* __restrict__ xlt, const float* __restrict__ logits,
    const float* __restrict__ cbias, const int* __restrict__ row_start,
    const int* __restrict__ csr_src, short* __restrict__ hout) {
  __shared__ float alpha_s[4][64];
  int lane = threadIdx.x & 63;
  int wid = threadIdx.x >> 6;
  int n = blockIdx.x * 4 + wid;
  if (n >= NNODES) return;
  int beg = row_start[n], end = row_start[n + 1];

  // stage 1: online softmax stats; lane = (eo, hm); merged per-head over eo
  int eo = lane >> 3, hm = lane & 7;
  float m = -1e30f, ssum = 0.f;
  for (int e = beg + eo; e < end; e += 8) {
    float lg = logits[(size_t)e * 8 + hm];
    float nm = fmaxf(m, lg);
    ssum = ssum * __expf(m - nm) + __expf(lg - nm);
    m = nm;
  }
  #pragma unroll
  for (int st = 8; st <= 32; st <<= 1) {
    float om = __shfl_xor(m, st, 64);
    float os = __shfl_xor(ssum, st, 64);
    float nm = fmaxf(m, om);
    ssum = ssum * __expf(m - nm) + os * __expf(om - nm);
    m = nm;
  }
  float rinv = 1.0f / (ssum + 1e-16f);  // per-lane: stats for head hm

  // stage 2: 8-edge groups; lane (eo,hm) computes one alpha -> LDS broadcast
  float o0 = 0.f, o1 = 0.f, o2 = 0.f, o3 = 0.f, o4 = 0.f, o5 = 0.f, o6 = 0.f;
  for (int g = beg; g < end; g += 8) {
    int e = g + eo;
    float al = 0.f;
    if (e < end) al = __expf(logits[(size_t)e * 8 + hm] - m) * rinv;
    alpha_s[wid][eo * 8 + hm] = al;
    int lim = end - g;
    if (lim > 8) lim = 8;
    for (int t = 0; t < lim; ++t) {
      int s = csr_src[g + t];
      uint4 xv = *(const uint4*)(xlt + (size_t)s * HCP + lane * 8);
      float4 aA = *(const float4*)&alpha_s[wid][t * 8];
      float4 aB = *(const float4*)&alpha_s[wid][t * 8 + 4];
      o0 += aA.x * bf_lo(xv.x);
      o1 += aA.y * bf_hi(xv.x);
      o2 += aA.z * bf_lo(xv.y);
      o3 += aA.w * bf_hi(xv.y);
      o4 += aB.x * bf_lo(xv.z);
      o5 += aB.y * bf_hi(xv.z);
      o6 += aB.z * bf_lo(xv.w);
    }
  }

  float accv = o0 + o1 + o2 + o3 + o4 + o5 + o6;
  float v = accv * (1.0f / 7.0f) + cbias[lane];
  hout[(size_t)n * 64 + lane] =
      __bfloat16_as_short(__float2bfloat16(fmaxf(v, 0.f)));
}

// ---------------------------------------------------------------------------
// Output MLP 64->32->16->9 + log_softmax, wave per node, 4 nodes per block.
// ---------------------------------------------------------------------------
__global__ __launch_bounds__(256) void out_mlp_kernel(
    const short* __restrict__ h, const float* __restrict__ V1,
    const float* __restrict__ c1, const float* __restrict__ V2,
    const float* __restrict__ c2, const float* __restrict__ V3,
    const float* __restrict__ c3, float* __restrict__ out) {
  __shared__ float hb[4][64], r1[4][32], r2[4][16], z3[4][9];
  int wid = threadIdx.x >> 6;
  int t = threadIdx.x & 63;
  int n = blockIdx.x * 4 + wid;
  hb[wid][t] =
      __uint_as_float(((unsigned)((const unsigned short*)h)[(size_t)n * 64 + t]) << 16);
  __syncthreads();
  if (t < 32) {
    float a = c1[t];
    #pragma unroll
    for (int k = 0; k < 64; ++k) a += hb[wid][k] * V1[k * 32 + t];
    r1[wid][t] = fmaxf(a, 0.f);
  }
  __syncthreads();
  if (t < 16) {
    float a = c2[t];
    #pragma unroll
    for (int k = 0; k < 32; ++k) a += r1[wid][k] * V2[k * 16 + t];
    r2[wid][t] = fmaxf(a, 0.f);
  }
  __syncthreads();
  if (t < 9) {
    float a = c3[t];
    #pragma unroll
    for (int k = 0; k < 16; ++k) a += r2[wid][k] * V3[k * 9 + t];
    z3[wid][t] = a;
  }
  __syncthreads();
  if (t < 9) {
    float mx = z3[wid][0];
    #pragma unroll
    for (int k = 1; k < 9; ++k) mx = fmaxf(mx, z3[wid][k]);
    float s = 0.f;
    #pragma unroll
    for (int k = 0; k < 9; ++k) s += __expf(z3[wid][k] - mx);
    out[(size_t)n * 9 + t] = z3[wid][t] - mx - logf(s);
  }
}

// ---------------------------------------------------------------------------
extern "C" void kernel_launch(void* const* d_in, const int* in_sizes, int n_in,
                              void* d_out, int out_size, void* d_ws, size_t ws_size,
                              hipStream_t stream) {
  const float* x   = (const float*)d_in[0];
  const int*   ei  = (const int*)d_in[1];
  const float* W1  = (const float*)d_in[2];
  const float* b1  = (const float*)d_in[3];
  const float* W2  = (const float*)d_in[4];
  const float* b2  = (const float*)d_in[5];
  const float* W3  = (const float*)d_in[6];
  const float* b3  = (const float*)d_in[7];
  const float* Wl  = (const float*)d_in[8];
  const float* bl  = (const float*)d_in[9];
  const float* Wr  = (const float*)d_in[10];
  const float* att = (const float*)d_in[11];
  const float* cb  = (const float*)d_in[12];
  const float* V1  = (const float*)d_in[13];
  const float* c1  = (const float*)d_in[14];
  const float* V2  = (const float*)d_in[15];
  const float* c2  = (const float*)d_in[16];
  const float* V3  = (const float*)d_in[17];
  const float* c3  = (const float*)d_in[18];
  float* out = (float*)d_out;

  char* ws = (char*)d_ws;
  size_t off = 0;
  auto alloc = [&](size_t bytes) {
    void* p = ws + off;
    off = (off + bytes + 255) & ~(size_t)255;
    return p;
  };
  // region0 (reused): xb (20.5MB) -> h2 -> xlt [N][1024] shorts
  char* region0 = (char*)alloc((size_t)NNODES * 1024 * 2 + 1024);
  short* xb  = (short*)region0;
  short* h2  = (short*)region0;
  short* xlt = (short*)region0;
  // region1 (reused): h1 (10.2MB) -> hA/hB
  char* region1 = (char*)alloc((size_t)NNODES * 512 * 2 + 1024);
  short* h1 = (short*)region1;
  short* hA = (short*)region1;
  short* hB = hA + (size_t)NNODES * 64;
  // persistent
  short* W1t = (short*)alloc((size_t)512 * 1024 * 2);
  short* W2t = (short*)alloc((size_t)256 * 512 * 2);
  short* W3t = (short*)alloc((size_t)64 * 256 * 2);
  short* Wgt = (short*)alloc((size_t)5 * HCP * 64 * 2);
  float* bg  = (float*)alloc((size_t)5 * HCP * 4);
  int* cnt       = (int*)alloc((size_t)NNODES * 4);
  int* row_start = (int*)alloc((size_t)(NNODES + 1) * 4);
  int* cursor    = (int*)alloc((size_t)NNODES * 4);
  int* csr_src   = (int*)alloc((size_t)ETOT * 4);
  int* csr_dst   = (int*)alloc((size_t)ETOT * 4);
  float* logits  = (float*)alloc((size_t)ETOT * 8 * 4);

  // ---- pack / convert
  convert_f32_bf16<<<(NNODES * 1024 / 4 + 255) / 256, 256, 0, stream>>>(
      x, xb, NNODES * 1024 / 4);
  transpose_bf16<<<(1024 * 512 + 255) / 256, 256, 0, stream>>>(W1, W1t, 1024, 512);
  transpose_bf16<<<(512 * 256 + 255) / 256, 256, 0, stream>>>(W2, W2t, 512, 256);
  transpose_bf16<<<(256 * 64 + 255) / 256, 256, 0, stream>>>(W3, W3t, 256, 64);
  pack_gat<<<(5 * HCP * 64 + 255) / 256, 256, 0, stream>>>(Wl, Wr, bl, Wgt, bg);

  // ---- CSR build (self-loops included)
  init_cnt<<<(NNODES + 255) / 256, 256, 0, stream>>>(cnt);
  hist_kernel<<<(NEDGES + 255) / 256, 256, 0, stream>>>(ei, cnt);
  scan_kernel<<<1, 1024, 0, stream>>>(cnt, row_start, cursor);
  scatter_self<<<(NNODES + 255) / 256, 256, 0, stream>>>(cursor, csr_src, csr_dst);
  scatter_kernel<<<(NEDGES + 255) / 256, 256, 0, stream>>>(ei, cursor, csr_src, csr_dst);

  // ---- input MLP (bf16 MFMA)
  mfma_gemm<64, 128, 1><<<dim3(157, 4), 256, 0, stream>>>(
      xb, W1t, b1, h1, NNODES, 1024, 512);
  mfma_gemm<64, 128, 1><<<dim3(157, 2), 256, 0, stream>>>(
      h1, W2t, b2, h2, NNODES, 512, 256);
  mfma_gemm<64, 64, 1><<<dim3(157, 1), 256, 0, stream>>>(
      h2, W3t, b3, hA, NNODES, 256, 64);

  // ---- 5 GATv2 layers
  short* hcur = hA;
  short* hnext = hB;
  for (int layer = 0; layer < 5; ++layer) {
    mfma_gemm<128, 128, 0><<<dim3(79, 8), 256, 0, stream>>>(
        hcur, Wgt + (size_t)layer * HCP * 64, bg + (size_t)layer * HCP, xlt,
        NNODES, 64, HCP);
    edge_logits_kernel<<<(ETOT + 31) / 32, 256, 0, stream>>>(
        xlt, att + (size_t)layer * HC, csr_src, csr_dst, logits);
    gat_agg2_kernel<<<2500, 256, 0, stream>>>(
        xlt, logits, cb + (size_t)layer * 64, row_start, csr_src, hnext);
    short* tmp = hcur; hcur = hnext; hnext = tmp;
  }

  // ---- output MLP + log_softmax
  out_mlp_kernel<<<2500, 256, 0, stream>>>(hcur, V1, c1, V2, c2, V3, c3, out);
}